// Round 11
// baseline (216.101 us; speedup 1.0000x reference)
//
#include <hip/hip_runtime.h>
#include <math.h>

typedef _Float16 half8 __attribute__((ext_vector_type(8)));
typedef float    f32x4 __attribute__((ext_vector_type(4)));

#define NROWS 16384
#define DIMS  512
#define KC    8192
#define DELTA 0.5f

__device__ inline unsigned fkey(float v) {
    unsigned u = __float_as_uint(v);
    return (u & 0x80000000u) ? ~u : (u | 0x80000000u);
}
__device__ inline float unfkey(unsigned u) {
    return (u & 0x80000000u) ? __uint_as_float(u & 0x7FFFFFFFu)
                             : __uint_as_float(~u);
}
__device__ inline unsigned umin_(unsigned a, unsigned b) { return a < b ? a : b; }
__device__ inline unsigned umax_(unsigned a, unsigned b) { return a > b ? a : b; }

// ---------------------------------------------------------------------------
// K0: fused prep. blocks [0,1024): cvt z panels; [1024,1536): cvt emb panels;
// [1536,3584): emb row sum-of-squares (fp64 accum).
// Packed layout (halfs): p*131072 + s*8192 + c*8, chunk c = f*64 + lg*16 + rr
// (p = 256-row panel, s = K-step of 32, f = 16-row fragment, lg = k-group,
// rr = row-in-fragment). 1KB fragment chunk read at +lane*16 is lane-linear.
// ---------------------------------------------------------------------------
__global__ __launch_bounds__(256)
void prep_kernel(const float* __restrict__ z, const float* __restrict__ emb,
                 _Float16* __restrict__ zh16, _Float16* __restrict__ eh16,
                 float* __restrict__ esf)
{
    int b = blockIdx.x, t = threadIdx.x;
    if (b < 1536) {
        const float* src;
        _Float16* dst;
        int pb;
        if (b < 1024) { src = z;   dst = zh16; pb = b; }
        else          { src = emb; dst = eh16; pb = b - 1024; }
        int p = pb >> 4, s = pb & 15;
        _Float16* dbase = dst + (size_t)p * 131072 + s * 8192;
        #pragma unroll
        for (int q = 0; q < 4; ++q) {
            int c = q * 256 + t;
            int f = c >> 6, lg = (c >> 4) & 3, rr = c & 15;
            int row = p * 256 + f * 16 + rr;
            const float* sp = src + (size_t)row * DIMS + s * 32 + lg * 8;
            float4 v0 = *(const float4*)(sp + 0);
            float4 v1 = *(const float4*)(sp + 4);
            half8 h;
            h[0] = (_Float16)v0.x; h[1] = (_Float16)v0.y;
            h[2] = (_Float16)v0.z; h[3] = (_Float16)v0.w;
            h[4] = (_Float16)v1.x; h[5] = (_Float16)v1.y;
            h[6] = (_Float16)v1.z; h[7] = (_Float16)v1.w;
            *(half8*)(dbase + c * 8) = h;
        }
    } else {
        int b2 = b - 1536;
        int w = b2 * 4 + (t >> 6);
        int lane = t & 63;
        const float* r = emb + (size_t)w * DIMS;
        float4 v0 = *(const float4*)(r + lane * 4);
        float4 v1 = *(const float4*)(r + 256 + lane * 4);
        double s = (double)v0.x * v0.x + (double)v0.y * v0.y +
                   (double)v0.z * v0.z + (double)v0.w * v0.w +
                   (double)v1.x * v1.x + (double)v1.y * v1.y +
                   (double)v1.z * v1.z + (double)v1.w * v1.w;
        #pragma unroll
        for (int off = 32; off; off >>= 1) s += __shfl_down(s, off);
        if (lane == 0) esf[w] = (float)s;
    }
}

// ---------------------------------------------------------------------------
// K1: fp16 screen GEMM, 8-phase counted-vmcnt structure (m201 port).
// 256x256 block, 512 threads = 8 waves (2M x 4N), wave tile 128x64
// (acc = 32 frags = 128 AGPR). 3-half-buffer ring (3 x 32KB: A 16K | B 16K),
// 2 phases per K-step:
//   P1: ds_read af[0..3],bf[0..3] (8); 2 A-gloads (kstep s+2); barrier;
//       lgkmcnt(0)+sched_barrier; setprio1; MFMA i0-3 x j0-3; setprio0; barrier
//   P2: ds_read af[4..7] (4); 2 B-gloads (s+2); [vmcnt(4) after MFMA];
//       barrier; ... MFMA i4-7 x j0-3 ...; barrier
// vmcnt(4) once per K-step (end P2): drains kstep s+1's 4 loads, keeps
// s+2's 4 in flight (never 0 until the s==14 boundary).
// Safety: ring target (s+2)%3 == (s-1)%3 was last ds_read in kstep s-1,
// whose reads all waves drained (lgkmcnt0) before its end barrier; the
// end-P2 vmcnt(4)+barrier guarantees cross-wave landing of kstep s+1.
// Fragment reads lane-linear (packed layout): zero bank conflicts.
// tab entry u64 = k1<<32 | k2 (truncated keys fkey&~127 | col7, col local
// to each 128-col half) -> format identical to R10, collect unchanged.
// ---------------------------------------------------------------------------
__global__ __launch_bounds__(512, 2)
void screen_kernel(const char* __restrict__ zh, const char* __restrict__ eh,
                   const float* __restrict__ esf,
                   unsigned long long* __restrict__ tab)
{
    __shared__ char smem[135168];  // ring 3x32KB = 96KB; epilogue table 132KB

    const int t    = threadIdx.x;
    const int lane = t & 63;
    const int wave = t >> 6;
    const int lg   = lane >> 4;
    const int lr   = lane & 15;
    const int wm   = wave >> 2;      // 0..1 row half (128 rows)
    const int wn   = wave & 3;       // 0..3 col quarter (64 cols)
    const int by   = blockIdx.x;     // col panel 0..31 (fast dim)
    const int bx   = blockIdx.y;     // row panel 0..63

    const char* gA = zh + (size_t)bx * 262144;
    const char* gB = eh + (size_t)by * 262144;

    f32x4 acc[8][4];
    #pragma unroll
    for (int i = 0; i < 8; ++i)
        #pragma unroll
        for (int j = 0; j < 4; ++j)
            acc[i][j] = (f32x4){0.f, 0.f, 0.f, 0.f};

    typedef const __attribute__((address_space(1))) unsigned int gq_t;
    typedef __attribute__((address_space(3))) unsigned int lq_t;
    // two 8KB rounds; src = gX + s*16384 + r*8192 + t*16 (t*16 = wave*1024
    // + lane*16 -> dst base wave-uniform)
    #define G2A(dstbuf, s)                                                    \
    {                                                                         \
        _Pragma("unroll")                                                     \
        for (int r = 0; r < 2; ++r)                                           \
            __builtin_amdgcn_global_load_lds(                                 \
                (gq_t*)(gA + (size_t)(s) * 16384 + r * 8192 + t * 16),        \
                (lq_t*)((dstbuf) + r * 8192 + wave * 1024 + lane * 16),       \
                16, 0, 0);                                                    \
    }
    #define G2B(dstbuf, s)                                                    \
    {                                                                         \
        _Pragma("unroll")                                                     \
        for (int r = 0; r < 2; ++r)                                           \
            __builtin_amdgcn_global_load_lds(                                 \
                (gq_t*)(gB + (size_t)(s) * 16384 + r * 8192 + t * 16),        \
                (lq_t*)((dstbuf) + 16384 + r * 8192 + wave * 1024 + lane * 16),\
                16, 0, 0);                                                    \
    }

    char* p0 = smem;            // kstep s   (being computed)
    char* p1 = smem + 32768;    // kstep s+1 (landing)
    char* p2 = smem + 65536;    // kstep s+2 (being staged)

    // prologue: stage ksteps 0 and 1
    G2A(p0, 0); G2B(p0, 0);
    G2A(p1, 1); G2B(p1, 1);
    asm volatile("s_waitcnt vmcnt(4)" ::: "memory");   // kstep 0 landed
    __builtin_amdgcn_s_barrier();

    #pragma unroll 1
    for (int s = 0; s < 16; ++s) {
        const char* Ab = p0 + lane * 16;
        const char* Bb = p0 + 16384 + lane * 16;
        half8 af[8], bf[4];

        // ---- phase 1: af[0..3], bf[0..3]; MFMA (i0-3 x j0-3) ----
        #pragma unroll
        for (int i = 0; i < 4; ++i)
            af[i] = *(const half8*)(Ab + (wm * 8 + i) * 1024);
        #pragma unroll
        for (int j = 0; j < 4; ++j)
            bf[j] = *(const half8*)(Bb + (wn * 4 + j) * 1024);
        if (s < 14) G2A(p2, s + 2);
        __builtin_amdgcn_s_barrier();
        asm volatile("s_waitcnt lgkmcnt(0)" ::: "memory");
        __builtin_amdgcn_sched_barrier(0);
        __builtin_amdgcn_s_setprio(1);
        #pragma unroll
        for (int i = 0; i < 4; ++i)
            #pragma unroll
            for (int j = 0; j < 4; ++j)
                acc[i][j] = __builtin_amdgcn_mfma_f32_16x16x32_f16(
                    af[i], bf[j], acc[i][j], 0, 0, 0);
        __builtin_amdgcn_s_setprio(0);
        __builtin_amdgcn_s_barrier();

        // ---- phase 2: af[4..7]; MFMA (i4-7 x j0-3) ----
        #pragma unroll
        for (int i = 4; i < 8; ++i)
            af[i] = *(const half8*)(Ab + (wm * 8 + i) * 1024);
        if (s < 14) G2B(p2, s + 2);
        __builtin_amdgcn_s_barrier();
        asm volatile("s_waitcnt lgkmcnt(0)" ::: "memory");
        __builtin_amdgcn_sched_barrier(0);
        __builtin_amdgcn_s_setprio(1);
        #pragma unroll
        for (int i = 4; i < 8; ++i)
            #pragma unroll
            for (int j = 0; j < 4; ++j)
                acc[i][j] = __builtin_amdgcn_mfma_f32_16x16x32_f16(
                    af[i], bf[j], acc[i][j], 0, 0, 0);
        __builtin_amdgcn_s_setprio(0);
        if (s < 14)       asm volatile("s_waitcnt vmcnt(4)" ::: "memory");
        else if (s == 14) asm volatile("s_waitcnt vmcnt(0)" ::: "memory");
        __builtin_amdgcn_s_barrier();

        char* tmp = p0; p0 = p1; p1 = p2; p2 = tmp;
    }

    // ---- epilogue pass 1: per-thread top-2-of-4, truncated u32 keys ----
    unsigned long long* mb = (unsigned long long*)smem;  // [256][66] u64
    float es_j[4];
    #pragma unroll
    for (int j = 0; j < 4; ++j)
        es_j[j] = esf[by * 256 + wn * 64 + j * 16 + lr];

    #pragma unroll
    for (int i = 0; i < 8; ++i) {
        #pragma unroll
        for (int r = 0; r < 4; ++r) {
            unsigned k[4];
            #pragma unroll
            for (int j = 0; j < 4; ++j) {
                float v = fmaf(-2.f, acc[i][j][r], es_j[j]);
                // col local to the 128-half: (wn&1)*64 + j*16 + lr
                k[j] = (fkey(v) & 0xFFFFFF80u)
                     | (unsigned)((wn & 1) * 64 + j * 16 + lr);
            }
            unsigned lo1 = umin_(k[0], k[1]), hi1 = umax_(k[0], k[1]);
            unsigned lo2 = umin_(k[2], k[3]), hi2 = umax_(k[2], k[3]);
            unsigned k1 = umin_(lo1, lo2);
            unsigned k2 = umin_(umax_(lo1, lo2), umin_(hi1, hi2));
            int row = wm * 128 + i * 16 + lg * 4 + r;
            mb[row * 66 + wn * 16 + lr] =
                ((unsigned long long)k1 << 32) | k2;
        }
    }
    __syncthreads();

    // ---- epilogue pass 2: 512 threads, (row, 128-half) each ----
    {
        int row = t >> 1, half = t & 1;
        unsigned b1 = 0xFFFFFFFFu, b2 = 0xFFFFFFFFu;
        #pragma unroll 4
        for (int q = 0; q < 32; ++q) {
            unsigned long long e = mb[row * 66 + half * 32 + q];
            unsigned e1 = (unsigned)(e >> 32), e2 = (unsigned)e;
            unsigned nb1 = umin_(b1, e1);
            b2 = umin_(umax_(b1, e1), umin_(b2, e2));
            b1 = nb1;
        }
        tab[((size_t)(bx * 256 + row)) * 64 + by * 2 + half] =
            ((unsigned long long)b1 << 32) | b2;
    }
}

// ---------------------------------------------------------------------------
// K2: fused collect + exact rescore, zero global atomics (unchanged).
// ---------------------------------------------------------------------------
__global__ __launch_bounds__(256)
void collect_rescore_kernel(const float* __restrict__ z,
                            const float* __restrict__ emb,
                            const float* __restrict__ esf,
                            const unsigned long long* __restrict__ tab,
                            unsigned long long* __restrict__ rowkey,
                            int* __restrict__ counts)
{
    int t = threadIdx.x, lane = t & 63;
    if (blockIdx.x < 32) counts[blockIdx.x * 256 + t] = 0;
    int row = blockIdx.x * 4 + (t >> 6);

    unsigned long long e = tab[(size_t)row * 64 + lane];
    unsigned k1 = (unsigned)(e >> 32), k2 = (unsigned)e;
    unsigned m = k1;
    #pragma unroll
    for (int mask = 1; mask <= 32; mask <<= 1) {
        unsigned o = (unsigned)__shfl_xor((int)m, mask, 64);
        m = umin_(m, o);
    }
    float thr = unfkey(m & 0xFFFFFF80u) + DELTA;
    bool c1 = unfkey(k1 & 0xFFFFFF80u) <= thr;
    bool c2 = unfkey(k2 & 0xFFFFFF80u) <= thr;
    unsigned long long m1 = __ballot(c1);
    unsigned long long m2 = __ballot(c2);

    const float4* zr = (const float4*)(z + (size_t)row * DIMS + lane * 8);
    float4 a0 = zr[0], a1 = zr[1];

    unsigned long long best = ~0ull;
    while (m1 | m2) {
        int src;
        unsigned kk;
        if (m1) {
            src = __ffsll((long long)m1) - 1;
            m1 &= m1 - 1;
            kk = (unsigned)__shfl((int)k1, src, 64);
        } else {
            src = __ffsll((long long)m2) - 1;
            m2 &= m2 - 1;
            kk = (unsigned)__shfl((int)k2, src, 64);
        }
        int col = src * 128 + (int)(kk & 127u);

        const float4* er = (const float4*)(emb + (size_t)col * DIMS + lane * 8);
        float4 b0 = er[0], b1v = er[1];
        float s = a0.x * b0.x;
        s = fmaf(a0.y, b0.y, s); s = fmaf(a0.z, b0.z, s);
        s = fmaf(a0.w, b0.w, s); s = fmaf(a1.x, b1v.x, s);
        s = fmaf(a1.y, b1v.y, s); s = fmaf(a1.z, b1v.z, s);
        s = fmaf(a1.w, b1v.w, s);
        #pragma unroll
        for (int mask = 32; mask; mask >>= 1) s += __shfl_xor(s, mask);
        float v = fmaf(-2.f, s, esf[col]);
        unsigned long long key =
            ((unsigned long long)fkey(v) << 32) | (unsigned)col;
        best = key < best ? key : best;
    }
    if (lane == 0) rowkey[row] = best;
}

// ---------------------------------------------------------------------------
// K3: gather + loss partials + index output + histogram (unchanged).
// ---------------------------------------------------------------------------
__global__ __launch_bounds__(256)
void gather_loss_kernel(const float* __restrict__ z, const float* __restrict__ emb,
                        const unsigned long long* __restrict__ rowkey,
                        float* __restrict__ outq, float* __restrict__ out_idx_f,
                        int* __restrict__ counts, float* __restrict__ bsums)
{
    int gid = blockIdx.x * 256 + threadIdx.x;
    int row = gid >> 7;
    int c4  = (gid & 127) << 2;
    int idx = (int)(rowkey[row] & 0xFFFFFFFFull);
    if ((gid & 127) == 0) {
        out_idx_f[row] = (float)idx;
        atomicAdd(&counts[idx], 1);
    }
    float4 e  = *(const float4*)&emb[(size_t)idx * DIMS + c4];
    float4 zv = *(const float4*)&z[(size_t)row * DIMS + c4];
    *(float4*)&outq[(size_t)row * DIMS + c4] = e;
    float dx = e.x - zv.x, dy = e.y - zv.y, dz = e.z - zv.z, dw = e.w - zv.w;
    float s = dx * dx + dy * dy + dz * dz + dw * dw;
    #pragma unroll
    for (int off = 32; off; off >>= 1) s += __shfl_down(s, off);
    __shared__ float wsum[4];
    if ((threadIdx.x & 63) == 0) wsum[threadIdx.x >> 6] = s;
    __syncthreads();
    if (threadIdx.x == 0)
        bsums[blockIdx.x] = wsum[0] + wsum[1] + wsum[2] + wsum[3];
}

// ---------------------------------------------------------------------------
// K4: finalize scalars: vq_loss and perplexity (unchanged).
// ---------------------------------------------------------------------------
__global__ __launch_bounds__(256)
void finalize_kernel(const int* __restrict__ counts, const float* __restrict__ bsums,
                     float* __restrict__ out_scalars)
{
    int t = threadIdx.x;
    double ls = 0.0, ps = 0.0;
    for (int i = t; i < 8192; i += 256) {
        ls += (double)bsums[i];
        double avg = (double)counts[i] * (1.0 / 16384.0);
        ps += avg * log(avg + 1e-10);
    }
    #pragma unroll
    for (int off = 32; off; off >>= 1) {
        ls += __shfl_down(ls, off);
        ps += __shfl_down(ps, off);
    }
    __shared__ double l4[4], p4[4];
    if ((t & 63) == 0) { l4[t >> 6] = ls; p4[t >> 6] = ps; }
    __syncthreads();
    if (t == 0) {
        double L = l4[0] + l4[1] + l4[2] + l4[3];
        double P = p4[0] + p4[1] + p4[2] + p4[3];
        out_scalars[0] = (float)(1.25 * L / 8388608.0);
        out_scalars[1] = (float)exp(-P);
    }
}

// ---------------------------------------------------------------------------
// ws layout (bytes):
//   rowkey u64[16384] @ 0       (131072)  (written by collect_rescore)
//   counts int[8192]  @ 131072  (32768)   (zeroed by collect_rescore)
//   bsums  f32[8192]  @ 164096  (32768)
//   esf    f32[8192]  @ 196864  (32768)
// d_out scratch reuse (consumed before gather overwrites):
//   zh16 @ 0 (16MB) | eh16 @ 16777216 (8MB) | tab @ 25165824 (8MB)
// d_out final (floats): quantized[8388608] | vq_loss | perplexity | idx[16384]
// ---------------------------------------------------------------------------
extern "C" void kernel_launch(void* const* d_in, const int* in_sizes, int n_in,
                              void* d_out, int out_size, void* d_ws, size_t ws_size,
                              hipStream_t stream)
{
    const float* z   = (const float*)d_in[0];
    const float* emb = (const float*)d_in[1];

    float* out         = (float*)d_out;
    float* outq        = out;
    float* out_scalars = out + 8388608;
    float* out_idx     = out + 8388610;

    char* ob = (char*)d_out;
    _Float16* zh16 = (_Float16*)(ob + 0);
    _Float16* eh16 = (_Float16*)(ob + 16777216);
    unsigned long long* tab = (unsigned long long*)(ob + 25165824);

    char* ws = (char*)d_ws;
    unsigned long long* rowkey = (unsigned long long*)(ws + 0);
    int*   counts = (int*)  (ws + 131072);
    float* bsums  = (float*)(ws + 164096);
    float* esf    = (float*)(ws + 196864);

    prep_kernel<<<3584, 256, 0, stream>>>(z, emb, zh16, eh16, esf);
    screen_kernel<<<dim3(32, 64), 512, 0, stream>>>((const char*)zh16,
                                                    (const char*)eh16, esf, tab);
    collect_rescore_kernel<<<4096, 256, 0, stream>>>(z, emb, esf, tab,
                                                     rowkey, counts);
    gather_loss_kernel<<<8192, 256, 0, stream>>>(z, emb, rowkey, outq, out_idx,
                                                 counts, bsums);
    finalize_kernel<<<1, 256, 0, stream>>>(counts, bsums, out_scalars);
}

// Round 12
// 200.694 us; speedup vs baseline: 1.0768x; 1.0768x over previous
//
#include <hip/hip_runtime.h>
#include <math.h>

typedef _Float16 half8 __attribute__((ext_vector_type(8)));
typedef float    f32x4 __attribute__((ext_vector_type(4)));

#define NROWS 16384
#define DIMS  512
#define KC    8192
#define DELTA 0.5f

__device__ inline unsigned fkey(float v) {
    unsigned u = __float_as_uint(v);
    return (u & 0x80000000u) ? ~u : (u | 0x80000000u);
}
__device__ inline float unfkey(unsigned u) {
    return (u & 0x80000000u) ? __uint_as_float(u & 0x7FFFFFFFu)
                             : __uint_as_float(~u);
}
__device__ inline unsigned umin_(unsigned a, unsigned b) { return a < b ? a : b; }
__device__ inline unsigned umax_(unsigned a, unsigned b) { return a > b ? a : b; }

// ---------------------------------------------------------------------------
// K0: fused prep. blocks [0,1024): cvt z panels; [1024,1536): cvt emb panels;
// [1536,3584): emb row sum-of-squares (fp64 accum).
// Packed layout (halfs): p*131072 + s*8192 + c*8, chunk c = f*64 + lg*16 + rr
// (p = 256-row panel, s = K-step of 32, f = 16-row fragment, lg = k-group,
// rr = row-in-fragment). 1KB fragment chunk read at +lane*16 is lane-linear.
// ---------------------------------------------------------------------------
__global__ __launch_bounds__(256)
void prep_kernel(const float* __restrict__ z, const float* __restrict__ emb,
                 _Float16* __restrict__ zh16, _Float16* __restrict__ eh16,
                 float* __restrict__ esf)
{
    int b = blockIdx.x, t = threadIdx.x;
    if (b < 1536) {
        const float* src;
        _Float16* dst;
        int pb;
        if (b < 1024) { src = z;   dst = zh16; pb = b; }
        else          { src = emb; dst = eh16; pb = b - 1024; }
        int p = pb >> 4, s = pb & 15;
        _Float16* dbase = dst + (size_t)p * 131072 + s * 8192;
        #pragma unroll
        for (int q = 0; q < 4; ++q) {
            int c = q * 256 + t;
            int f = c >> 6, lg = (c >> 4) & 3, rr = c & 15;
            int row = p * 256 + f * 16 + rr;
            const float* sp = src + (size_t)row * DIMS + s * 32 + lg * 8;
            float4 v0 = *(const float4*)(sp + 0);
            float4 v1 = *(const float4*)(sp + 4);
            half8 h;
            h[0] = (_Float16)v0.x; h[1] = (_Float16)v0.y;
            h[2] = (_Float16)v0.z; h[3] = (_Float16)v0.w;
            h[4] = (_Float16)v1.x; h[5] = (_Float16)v1.y;
            h[6] = (_Float16)v1.z; h[7] = (_Float16)v1.w;
            *(half8*)(dbase + c * 8) = h;
        }
    } else {
        int b2 = b - 1536;
        int w = b2 * 4 + (t >> 6);
        int lane = t & 63;
        const float* r = emb + (size_t)w * DIMS;
        float4 v0 = *(const float4*)(r + lane * 4);
        float4 v1 = *(const float4*)(r + 256 + lane * 4);
        double s = (double)v0.x * v0.x + (double)v0.y * v0.y +
                   (double)v0.z * v0.z + (double)v0.w * v0.w +
                   (double)v1.x * v1.x + (double)v1.y * v1.y +
                   (double)v1.z * v1.z + (double)v1.w * v1.w;
        #pragma unroll
        for (int off = 32; off; off >>= 1) s += __shfl_down(s, off);
        if (lane == 0) esf[w] = (float)s;
    }
}

// ---------------------------------------------------------------------------
// K1: fp16 screen GEMM + per-(row, 128-col-block) top-2 (truncated-key).
// 256x128 block, 4 waves (2Mx2N), wave tile 128x64 (i8 x j4), dbuf 48KB,
// 2 blocks/CU co-resident (m114 overlap covers the sync drain).
// Fragment reads lane-linear: conflict-free. This structure measured
// 167 us / MfmaUtil 36.5% (R10) and beat 3 phased-schedule variants
// (R5/R6/R11) — it is the local optimum for this tile/register shape.
// tab entry u64 = k1<<32 | k2 (truncated keys: fkey&~127 | col7, cols local
// to the 128-col block).
// ---------------------------------------------------------------------------
__global__ __launch_bounds__(256, 2)
void screen_kernel(const char* __restrict__ zh, const char* __restrict__ eh,
                   const float* __restrict__ esf,
                   unsigned long long* __restrict__ tab)
{
    __shared__ char smem[67584];   // dbuf 2x24KB; epilogue table 66KB

    const int t    = threadIdx.x;
    const int lane = t & 63;
    const int wave = t >> 6;
    const int lg   = lane >> 4;
    const int lr   = lane & 15;
    const int wm   = wave >> 1;      // 0..1 row half (128 rows)
    const int wn   = wave & 1;       // 0..1 col half (64 cols)
    const int by   = blockIdx.x;     // col block 0..63 (fast dim)
    const int bx   = blockIdx.y;     // row block 0..63

    const char* gA = zh + (size_t)bx * 262144;
    const char* gB = eh + (size_t)(by >> 1) * 262144 + (by & 1) * 8192;

    f32x4 acc[8][4];
    #pragma unroll
    for (int i = 0; i < 8; ++i)
        #pragma unroll
        for (int j = 0; j < 4; ++j)
            acc[i][j] = (f32x4){0.f, 0.f, 0.f, 0.f};

    typedef const __attribute__((address_space(1))) unsigned int gq_t;
    typedef __attribute__((address_space(3))) unsigned int lq_t;
    #define STAGE(dstbuf, s)                                                  \
    {                                                                         \
        const char* gsA = gA + (size_t)(s) * 16384;                          \
        const char* gsB = gB + (size_t)(s) * 16384;                          \
        _Pragma("unroll")                                                     \
        for (int k = 0; k < 4; ++k) {                                        \
            int off = k * 4096 + wave * 1024;                                \
            __builtin_amdgcn_global_load_lds(                                 \
                (gq_t*)(gsA + off + lane * 16),                               \
                (lq_t*)((dstbuf) + off), 16, 0, 0);                           \
        }                                                                     \
        _Pragma("unroll")                                                     \
        for (int k = 0; k < 2; ++k) {                                        \
            int off = k * 4096 + wave * 1024;                                \
            __builtin_amdgcn_global_load_lds(                                 \
                (gq_t*)(gsB + off + lane * 16),                               \
                (lq_t*)((dstbuf) + 16384 + off), 16, 0, 0);                   \
        }                                                                     \
    }
    #define COMPUTE(buf)                                                      \
    {                                                                         \
        const char* Ab = (buf) + (wm * 8) * 1024 + lane * 16;                 \
        const char* Bb = (buf) + 16384 + (wn * 4) * 1024 + lane * 16;         \
        half8 af[8], bf[4];                                                   \
        _Pragma("unroll")                                                     \
        for (int i = 0; i < 8; ++i) af[i] = *(const half8*)(Ab + i * 1024);   \
        _Pragma("unroll")                                                     \
        for (int j = 0; j < 4; ++j) bf[j] = *(const half8*)(Bb + j * 1024);   \
        _Pragma("unroll")                                                     \
        for (int i = 0; i < 8; ++i)                                           \
            _Pragma("unroll")                                                 \
            for (int j = 0; j < 4; ++j)                                       \
                acc[i][j] = __builtin_amdgcn_mfma_f32_16x16x32_f16(           \
                    af[i], bf[j], acc[i][j], 0, 0, 0);                        \
    }

    char* p0 = smem;
    char* p1 = smem + 24576;
    STAGE(p0, 0);
    __syncthreads();

    #pragma unroll 1
    for (int s = 0; s < 16; s += 2) {
        STAGE(p1, s + 1);
        COMPUTE(p0);
        __syncthreads();
        if (s + 2 < 16) STAGE(p0, s + 2);
        COMPUTE(p1);
        __syncthreads();
    }

    // ---- epilogue pass 1: per-thread top-2-of-4, truncated u32 keys ----
    unsigned long long* mb = (unsigned long long*)smem;  // stride 33/row
    float es_j[4];
    #pragma unroll
    for (int j = 0; j < 4; ++j)
        es_j[j] = esf[by * 128 + wn * 64 + j * 16 + lr];

    #pragma unroll
    for (int i = 0; i < 8; ++i) {
        #pragma unroll
        for (int r = 0; r < 4; ++r) {
            unsigned k[4];
            #pragma unroll
            for (int j = 0; j < 4; ++j) {
                float v = fmaf(-2.f, acc[i][j][r], es_j[j]);
                k[j] = (fkey(v) & 0xFFFFFF80u)
                     | (unsigned)(wn * 64 + j * 16 + lr);
            }
            unsigned lo1 = umin_(k[0], k[1]), hi1 = umax_(k[0], k[1]);
            unsigned lo2 = umin_(k[2], k[3]), hi2 = umax_(k[2], k[3]);
            unsigned k1 = umin_(lo1, lo2);
            unsigned k2 = umin_(umax_(lo1, lo2), umin_(hi1, hi2));
            int row = wm * 128 + i * 16 + lg * 4 + r;
            mb[row * 33 + wn * 16 + lr] =
                ((unsigned long long)k1 << 32) | k2;
        }
    }
    __syncthreads();

    // ---- epilogue pass 2: one row per thread, merge 32 sorted pairs ----
    {
        unsigned b1 = 0xFFFFFFFFu, b2 = 0xFFFFFFFFu;
        #pragma unroll 4
        for (int q = 0; q < 32; ++q) {
            unsigned long long e = mb[t * 33 + q];
            unsigned e1 = (unsigned)(e >> 32), e2 = (unsigned)e;
            unsigned nb1 = umin_(b1, e1);
            b2 = umin_(umax_(b1, e1), umin_(b2, e2));
            b1 = nb1;
        }
        tab[((size_t)(bx * 256 + t)) * 64 + by] =
            ((unsigned long long)b1 << 32) | b2;
    }
}

// ---------------------------------------------------------------------------
// K2: fused collect + exact rescore, ZERO global atomics.
// One wave per row: shuffle-min over 64 tab keys -> threshold; ballot the
// candidate lanes; loop over set bits (~1 iter/row): broadcast col, all 64
// lanes cooperatively fp32-dot z[row].emb[col], fold min-key; lane 0 stores
// rowkey[row]. Also zeroes counts.
// ---------------------------------------------------------------------------
__global__ __launch_bounds__(256)
void collect_rescore_kernel(const float* __restrict__ z,
                            const float* __restrict__ emb,
                            const float* __restrict__ esf,
                            const unsigned long long* __restrict__ tab,
                            unsigned long long* __restrict__ rowkey,
                            int* __restrict__ counts)
{
    int t = threadIdx.x, lane = t & 63;
    if (blockIdx.x < 32) counts[blockIdx.x * 256 + t] = 0;
    int row = blockIdx.x * 4 + (t >> 6);

    unsigned long long e = tab[(size_t)row * 64 + lane];
    unsigned k1 = (unsigned)(e >> 32), k2 = (unsigned)e;
    unsigned m = k1;
    #pragma unroll
    for (int mask = 1; mask <= 32; mask <<= 1) {
        unsigned o = (unsigned)__shfl_xor((int)m, mask, 64);
        m = umin_(m, o);
    }
    float thr = unfkey(m & 0xFFFFFF80u) + DELTA;
    bool c1 = unfkey(k1 & 0xFFFFFF80u) <= thr;
    bool c2 = unfkey(k2 & 0xFFFFFF80u) <= thr;
    unsigned long long m1 = __ballot(c1);
    unsigned long long m2 = __ballot(c2);

    const float4* zr = (const float4*)(z + (size_t)row * DIMS + lane * 8);
    float4 a0 = zr[0], a1 = zr[1];

    unsigned long long best = ~0ull;
    while (m1 | m2) {
        int src;
        unsigned kk;
        if (m1) {
            src = __ffsll((long long)m1) - 1;
            m1 &= m1 - 1;
            kk = (unsigned)__shfl((int)k1, src, 64);
        } else {
            src = __ffsll((long long)m2) - 1;
            m2 &= m2 - 1;
            kk = (unsigned)__shfl((int)k2, src, 64);
        }
        int col = src * 128 + (int)(kk & 127u);

        const float4* er = (const float4*)(emb + (size_t)col * DIMS + lane * 8);
        float4 b0 = er[0], b1v = er[1];
        float s = a0.x * b0.x;
        s = fmaf(a0.y, b0.y, s); s = fmaf(a0.z, b0.z, s);
        s = fmaf(a0.w, b0.w, s); s = fmaf(a1.x, b1v.x, s);
        s = fmaf(a1.y, b1v.y, s); s = fmaf(a1.z, b1v.z, s);
        s = fmaf(a1.w, b1v.w, s);
        #pragma unroll
        for (int mask = 32; mask; mask >>= 1) s += __shfl_xor(s, mask);
        float v = fmaf(-2.f, s, esf[col]);
        unsigned long long key =
            ((unsigned long long)fkey(v) << 32) | (unsigned)col;
        best = key < best ? key : best;
    }
    if (lane == 0) rowkey[row] = best;
}

// ---------------------------------------------------------------------------
// K3: gather + loss partials + index output + histogram.
// ---------------------------------------------------------------------------
__global__ __launch_bounds__(256)
void gather_loss_kernel(const float* __restrict__ z, const float* __restrict__ emb,
                        const unsigned long long* __restrict__ rowkey,
                        float* __restrict__ outq, float* __restrict__ out_idx_f,
                        int* __restrict__ counts, float* __restrict__ bsums)
{
    int gid = blockIdx.x * 256 + threadIdx.x;
    int row = gid >> 7;
    int c4  = (gid & 127) << 2;
    int idx = (int)(rowkey[row] & 0xFFFFFFFFull);
    if ((gid & 127) == 0) {
        out_idx_f[row] = (float)idx;
        atomicAdd(&counts[idx], 1);
    }
    float4 e  = *(const float4*)&emb[(size_t)idx * DIMS + c4];
    float4 zv = *(const float4*)&z[(size_t)row * DIMS + c4];
    *(float4*)&outq[(size_t)row * DIMS + c4] = e;
    float dx = e.x - zv.x, dy = e.y - zv.y, dz = e.z - zv.z, dw = e.w - zv.w;
    float s = dx * dx + dy * dy + dz * dz + dw * dw;
    #pragma unroll
    for (int off = 32; off; off >>= 1) s += __shfl_down(s, off);
    __shared__ float wsum[4];
    if ((threadIdx.x & 63) == 0) wsum[threadIdx.x >> 6] = s;
    __syncthreads();
    if (threadIdx.x == 0)
        bsums[blockIdx.x] = wsum[0] + wsum[1] + wsum[2] + wsum[3];
}

// ---------------------------------------------------------------------------
// K4: finalize scalars: vq_loss and perplexity
// ---------------------------------------------------------------------------
__global__ __launch_bounds__(256)
void finalize_kernel(const int* __restrict__ counts, const float* __restrict__ bsums,
                     float* __restrict__ out_scalars)
{
    int t = threadIdx.x;
    double ls = 0.0, ps = 0.0;
    for (int i = t; i < 8192; i += 256) {
        ls += (double)bsums[i];
        double avg = (double)counts[i] * (1.0 / 16384.0);
        ps += avg * log(avg + 1e-10);
    }
    #pragma unroll
    for (int off = 32; off; off >>= 1) {
        ls += __shfl_down(ls, off);
        ps += __shfl_down(ps, off);
    }
    __shared__ double l4[4], p4[4];
    if ((t & 63) == 0) { l4[t >> 6] = ls; p4[t >> 6] = ps; }
    __syncthreads();
    if (t == 0) {
        double L = l4[0] + l4[1] + l4[2] + l4[3];
        double P = p4[0] + p4[1] + p4[2] + p4[3];
        out_scalars[0] = (float)(1.25 * L / 8388608.0);
        out_scalars[1] = (float)exp(-P);
    }
}

// ---------------------------------------------------------------------------
// ws layout (bytes):
//   rowkey u64[16384] @ 0       (131072)  (written by collect_rescore)
//   counts int[8192]  @ 131072  (32768)   (zeroed by collect_rescore)
//   bsums  f32[8192]  @ 164096  (32768)
//   esf    f32[8192]  @ 196864  (32768)
// d_out scratch reuse (consumed before gather overwrites):
//   zh16 @ 0 (16MB) | eh16 @ 16777216 (8MB) | tab @ 25165824 (8MB)
// d_out final (floats): quantized[8388608] | vq_loss | perplexity | idx[16384]
// ---------------------------------------------------------------------------
extern "C" void kernel_launch(void* const* d_in, const int* in_sizes, int n_in,
                              void* d_out, int out_size, void* d_ws, size_t ws_size,
                              hipStream_t stream)
{
    const float* z   = (const float*)d_in[0];
    const float* emb = (const float*)d_in[1];

    float* out         = (float*)d_out;
    float* outq        = out;
    float* out_scalars = out + 8388608;
    float* out_idx     = out + 8388610;

    char* ob = (char*)d_out;
    _Float16* zh16 = (_Float16*)(ob + 0);
    _Float16* eh16 = (_Float16*)(ob + 16777216);
    unsigned long long* tab = (unsigned long long*)(ob + 25165824);

    char* ws = (char*)d_ws;
    unsigned long long* rowkey = (unsigned long long*)(ws + 0);
    int*   counts = (int*)  (ws + 131072);
    float* bsums  = (float*)(ws + 164096);
    float* esf    = (float*)(ws + 196864);

    prep_kernel<<<3584, 256, 0, stream>>>(z, emb, zh16, eh16, esf);
    screen_kernel<<<dim3(64, 64), 256, 0, stream>>>((const char*)zh16,
                                                    (const char*)eh16, esf, tab);
    collect_rescore_kernel<<<4096, 256, 0, stream>>>(z, emb, esf, tab,
                                                     rowkey, counts);
    gather_loss_kernel<<<8192, 256, 0, stream>>>(z, emb, rowkey, outq, out_idx,
                                                 counts, bsums);
    finalize_kernel<<<1, 256, 0, stream>>>(counts, bsums, out_scalars);
}

// Round 13
// 147.314 us; speedup vs baseline: 1.4669x; 1.3624x over previous
//
#include <hip/hip_runtime.h>
#include <math.h>

typedef int   i32x4 __attribute__((ext_vector_type(4)));

#define NROWS 16384
#define DIMS  512
#define KC    8192
#define DELTA 5.0f
#define QCLIP 4.5f

__device__ inline unsigned fkey(float v) {
    unsigned u = __float_as_uint(v);
    return (u & 0x80000000u) ? ~u : (u | 0x80000000u);
}
__device__ inline float unfkey(unsigned u) {
    return (u & 0x80000000u) ? __uint_as_float(u & 0x7FFFFFFFu)
                             : __uint_as_float(~u);
}
__device__ inline unsigned umin_(unsigned a, unsigned b) { return a < b ? a : b; }
__device__ inline unsigned umax_(unsigned a, unsigned b) { return a > b ? a : b; }

// ---------------------------------------------------------------------------
// K0: fused prep. blocks [0,512): quantize z -> i8 panels; [512,768): emb;
// [768,2816): emb row sum-of-squares (fp64 accum).
// Packed i8 layout (bytes): p*131072 + s*16384 + c*16, chunk c = f*64+lg*16+rr
// (p = 256-row panel, s = K-step of 64, f = 16-row fragment, lg = k-quarter,
// rr = row-in-fragment). A 1KB fragment chunk read at +lane*16 is lane-linear
// (lg = lane>>4, rr = lane&15). Quantization: round(x * 127/4.5), clip +-127.
// i32 MFMA accumulation is exact -> screen dist error sigma ~0.65 << DELTA.
// ---------------------------------------------------------------------------
__global__ __launch_bounds__(256)
void prep_kernel(const float* __restrict__ z, const float* __restrict__ emb,
                 signed char* __restrict__ zi8, signed char* __restrict__ ei8,
                 float* __restrict__ esf)
{
    const float QS = 127.0f / QCLIP;
    int b = blockIdx.x, t = threadIdx.x;
    if (b < 768) {
        const float* src;
        signed char* dst;
        int pb;
        if (b < 512) { src = z;   dst = zi8; pb = b; }
        else         { src = emb; dst = ei8; pb = b - 512; }
        int p = pb >> 3, s = pb & 7;
        signed char* dbase = dst + (size_t)p * 131072 + s * 16384;
        #pragma unroll
        for (int q = 0; q < 4; ++q) {
            int c = q * 256 + t;
            int f = c >> 6, lg = (c >> 4) & 3, rr = c & 15;
            int row = p * 256 + f * 16 + rr;
            const float* sp = src + (size_t)row * DIMS + s * 64 + lg * 16;
            float4 v0 = *(const float4*)(sp + 0);
            float4 v1 = *(const float4*)(sp + 4);
            float4 v2 = *(const float4*)(sp + 8);
            float4 v3 = *(const float4*)(sp + 12);
            float vv[16] = {v0.x, v0.y, v0.z, v0.w, v1.x, v1.y, v1.z, v1.w,
                            v2.x, v2.y, v2.z, v2.w, v3.x, v3.y, v3.z, v3.w};
            unsigned w[4];
            #pragma unroll
            for (int k = 0; k < 4; ++k) {
                unsigned r = 0;
                #pragma unroll
                for (int e = 0; e < 4; ++e) {
                    int qv = __float2int_rn(
                        fminf(fmaxf(vv[k * 4 + e] * QS, -127.f), 127.f));
                    r |= (unsigned)(qv & 255) << (e * 8);
                }
                w[k] = r;
            }
            *(i32x4*)(dbase + c * 16) =
                (i32x4){(int)w[0], (int)w[1], (int)w[2], (int)w[3]};
        }
    } else {
        int b2 = b - 768;
        int w = b2 * 4 + (t >> 6);
        int lane = t & 63;
        const float* r = emb + (size_t)w * DIMS;
        float4 v0 = *(const float4*)(r + lane * 4);
        float4 v1 = *(const float4*)(r + 256 + lane * 4);
        double s = (double)v0.x * v0.x + (double)v0.y * v0.y +
                   (double)v0.z * v0.z + (double)v0.w * v0.w +
                   (double)v1.x * v1.x + (double)v1.y * v1.y +
                   (double)v1.z * v1.z + (double)v1.w * v1.w;
        #pragma unroll
        for (int off = 32; off; off >>= 1) s += __shfl_down(s, off);
        if (lane == 0) esf[w] = (float)s;
    }
}

// ---------------------------------------------------------------------------
// K1: i8 screen GEMM + per-(row, 128-col-block) top-2 (truncated-key).
// Identical structure to the measured-optimal fp16 kernel (256x128 block,
// 4 waves 2Mx2N, wave tile 128x64, dbuf 48KB, 2 blocks/CU) but with
// mfma_i32_16x16x64_i8: 2x K per instruction -> 8 K-steps instead of 16,
// same per-step profile (12 ds_read_b128 + 32 MFMA + 24KB staged).
// A/B staged symmetrically -> internal k-permutation cancels; C/D layout
// dtype-independent. Fragment reads lane-linear: conflict-free.
// Epilogue: v = esf - 2*s^2*dot_i32 (s = 4.5/127); truncated u32 keys
// (fkey&~127 | col7); tab entry u64 = k1<<32 | k2.
// ---------------------------------------------------------------------------
__global__ __launch_bounds__(256, 2)
void screen_kernel(const char* __restrict__ zq, const char* __restrict__ eq,
                   const float* __restrict__ esf,
                   unsigned long long* __restrict__ tab)
{
    __shared__ char smem[67584];   // dbuf 2x24KB; epilogue table 66KB

    const int t    = threadIdx.x;
    const int lane = t & 63;
    const int wave = t >> 6;
    const int lg   = lane >> 4;
    const int lr   = lane & 15;
    const int wm   = wave >> 1;      // 0..1 row half (128 rows)
    const int wn   = wave & 1;       // 0..1 col half (64 cols)
    const int by   = blockIdx.x;     // col block 0..63 (fast dim)
    const int bx   = blockIdx.y;     // row block 0..63

    const char* gA = zq + (size_t)bx * 131072;
    const char* gB = eq + (size_t)(by >> 1) * 131072 + (by & 1) * 8192;

    i32x4 acc[8][4];
    #pragma unroll
    for (int i = 0; i < 8; ++i)
        #pragma unroll
        for (int j = 0; j < 4; ++j)
            acc[i][j] = (i32x4){0, 0, 0, 0};

    typedef const __attribute__((address_space(1))) unsigned int gq_t;
    typedef __attribute__((address_space(3))) unsigned int lq_t;
    // stage K-step s: A 16KB (4 rounds) + B 8KB (2 rounds); 6 gloads/thread
    #define STAGE(dstbuf, s)                                                  \
    {                                                                         \
        const char* gsA = gA + (size_t)(s) * 16384;                          \
        const char* gsB = gB + (size_t)(s) * 16384;                          \
        _Pragma("unroll")                                                     \
        for (int k = 0; k < 4; ++k) {                                        \
            int off = k * 4096 + wave * 1024;                                \
            __builtin_amdgcn_global_load_lds(                                 \
                (gq_t*)(gsA + off + lane * 16),                               \
                (lq_t*)((dstbuf) + off), 16, 0, 0);                           \
        }                                                                     \
        _Pragma("unroll")                                                     \
        for (int k = 0; k < 2; ++k) {                                        \
            int off = k * 4096 + wave * 1024;                                \
            __builtin_amdgcn_global_load_lds(                                 \
                (gq_t*)(gsB + off + lane * 16),                               \
                (lq_t*)((dstbuf) + 16384 + off), 16, 0, 0);                   \
        }                                                                     \
    }
    #define COMPUTE(buf)                                                      \
    {                                                                         \
        const char* Ab = (buf) + (wm * 8) * 1024 + lane * 16;                 \
        const char* Bb = (buf) + 16384 + (wn * 4) * 1024 + lane * 16;         \
        i32x4 af[8], bf[4];                                                   \
        _Pragma("unroll")                                                     \
        for (int i = 0; i < 8; ++i) af[i] = *(const i32x4*)(Ab + i * 1024);   \
        _Pragma("unroll")                                                     \
        for (int j = 0; j < 4; ++j) bf[j] = *(const i32x4*)(Bb + j * 1024);   \
        _Pragma("unroll")                                                     \
        for (int i = 0; i < 8; ++i)                                           \
            _Pragma("unroll")                                                 \
            for (int j = 0; j < 4; ++j)                                       \
                acc[i][j] = __builtin_amdgcn_mfma_i32_16x16x64_i8(            \
                    af[i], bf[j], acc[i][j], 0, 0, 0);                        \
    }

    char* p0 = smem;
    char* p1 = smem + 24576;
    STAGE(p0, 0);
    __syncthreads();

    #pragma unroll 1
    for (int s = 0; s < 8; s += 2) {
        STAGE(p1, s + 1);
        COMPUTE(p0);
        __syncthreads();
        if (s + 2 < 8) STAGE(p0, s + 2);
        COMPUTE(p1);
        __syncthreads();
    }

    // ---- epilogue pass 1: per-thread top-2-of-4, truncated u32 keys ----
    const float S2 = -2.0f * (QCLIP / 127.f) * (QCLIP / 127.f);
    unsigned long long* mb = (unsigned long long*)smem;  // stride 33/row
    float es_j[4];
    #pragma unroll
    for (int j = 0; j < 4; ++j)
        es_j[j] = esf[by * 128 + wn * 64 + j * 16 + lr];

    #pragma unroll
    for (int i = 0; i < 8; ++i) {
        #pragma unroll
        for (int r = 0; r < 4; ++r) {
            unsigned k[4];
            #pragma unroll
            for (int j = 0; j < 4; ++j) {
                float v = fmaf(S2, (float)acc[i][j][r], es_j[j]);
                k[j] = (fkey(v) & 0xFFFFFF80u)
                     | (unsigned)(wn * 64 + j * 16 + lr);
            }
            unsigned lo1 = umin_(k[0], k[1]), hi1 = umax_(k[0], k[1]);
            unsigned lo2 = umin_(k[2], k[3]), hi2 = umax_(k[2], k[3]);
            unsigned k1 = umin_(lo1, lo2);
            unsigned k2 = umin_(umax_(lo1, lo2), umin_(hi1, hi2));
            int row = wm * 128 + i * 16 + lg * 4 + r;
            mb[row * 33 + wn * 16 + lr] =
                ((unsigned long long)k1 << 32) | k2;
        }
    }
    __syncthreads();

    // ---- epilogue pass 2: one row per thread, merge 32 sorted pairs ----
    {
        unsigned b1 = 0xFFFFFFFFu, b2 = 0xFFFFFFFFu;
        #pragma unroll 4
        for (int q = 0; q < 32; ++q) {
            unsigned long long e = mb[t * 33 + q];
            unsigned e1 = (unsigned)(e >> 32), e2 = (unsigned)e;
            unsigned nb1 = umin_(b1, e1);
            b2 = umin_(umax_(b1, e1), umin_(b2, e2));
            b1 = nb1;
        }
        tab[((size_t)(bx * 256 + t)) * 64 + by] =
            ((unsigned long long)b1 << 32) | b2;
    }
}

// ---------------------------------------------------------------------------
// K2: fused collect + exact fp32 rescore, ZERO global atomics (unchanged).
// ---------------------------------------------------------------------------
__global__ __launch_bounds__(256)
void collect_rescore_kernel(const float* __restrict__ z,
                            const float* __restrict__ emb,
                            const float* __restrict__ esf,
                            const unsigned long long* __restrict__ tab,
                            unsigned long long* __restrict__ rowkey,
                            int* __restrict__ counts)
{
    int t = threadIdx.x, lane = t & 63;
    if (blockIdx.x < 32) counts[blockIdx.x * 256 + t] = 0;
    int row = blockIdx.x * 4 + (t >> 6);

    unsigned long long e = tab[(size_t)row * 64 + lane];
    unsigned k1 = (unsigned)(e >> 32), k2 = (unsigned)e;
    unsigned m = k1;
    #pragma unroll
    for (int mask = 1; mask <= 32; mask <<= 1) {
        unsigned o = (unsigned)__shfl_xor((int)m, mask, 64);
        m = umin_(m, o);
    }
    float thr = unfkey(m & 0xFFFFFF80u) + DELTA;
    bool c1 = unfkey(k1 & 0xFFFFFF80u) <= thr;
    bool c2 = unfkey(k2 & 0xFFFFFF80u) <= thr;
    unsigned long long m1 = __ballot(c1);
    unsigned long long m2 = __ballot(c2);

    const float4* zr = (const float4*)(z + (size_t)row * DIMS + lane * 8);
    float4 a0 = zr[0], a1 = zr[1];

    unsigned long long best = ~0ull;
    while (m1 | m2) {
        int src;
        unsigned kk;
        if (m1) {
            src = __ffsll((long long)m1) - 1;
            m1 &= m1 - 1;
            kk = (unsigned)__shfl((int)k1, src, 64);
        } else {
            src = __ffsll((long long)m2) - 1;
            m2 &= m2 - 1;
            kk = (unsigned)__shfl((int)k2, src, 64);
        }
        int col = src * 128 + (int)(kk & 127u);

        const float4* er = (const float4*)(emb + (size_t)col * DIMS + lane * 8);
        float4 b0 = er[0], b1v = er[1];
        float s = a0.x * b0.x;
        s = fmaf(a0.y, b0.y, s); s = fmaf(a0.z, b0.z, s);
        s = fmaf(a0.w, b0.w, s); s = fmaf(a1.x, b1v.x, s);
        s = fmaf(a1.y, b1v.y, s); s = fmaf(a1.z, b1v.z, s);
        s = fmaf(a1.w, b1v.w, s);
        #pragma unroll
        for (int mask = 32; mask; mask >>= 1) s += __shfl_xor(s, mask);
        float v = fmaf(-2.f, s, esf[col]);
        unsigned long long key =
            ((unsigned long long)fkey(v) << 32) | (unsigned)col;
        best = key < best ? key : best;
    }
    if (lane == 0) rowkey[row] = best;
}

// ---------------------------------------------------------------------------
// K3: gather + loss partials + index output + histogram (unchanged).
// ---------------------------------------------------------------------------
__global__ __launch_bounds__(256)
void gather_loss_kernel(const float* __restrict__ z, const float* __restrict__ emb,
                        const unsigned long long* __restrict__ rowkey,
                        float* __restrict__ outq, float* __restrict__ out_idx_f,
                        int* __restrict__ counts, float* __restrict__ bsums)
{
    int gid = blockIdx.x * 256 + threadIdx.x;
    int row = gid >> 7;
    int c4  = (gid & 127) << 2;
    int idx = (int)(rowkey[row] & 0xFFFFFFFFull);
    if ((gid & 127) == 0) {
        out_idx_f[row] = (float)idx;
        atomicAdd(&counts[idx], 1);
    }
    float4 e  = *(const float4*)&emb[(size_t)idx * DIMS + c4];
    float4 zv = *(const float4*)&z[(size_t)row * DIMS + c4];
    *(float4*)&outq[(size_t)row * DIMS + c4] = e;
    float dx = e.x - zv.x, dy = e.y - zv.y, dz = e.z - zv.z, dw = e.w - zv.w;
    float s = dx * dx + dy * dy + dz * dz + dw * dw;
    #pragma unroll
    for (int off = 32; off; off >>= 1) s += __shfl_down(s, off);
    __shared__ float wsum[4];
    if ((threadIdx.x & 63) == 0) wsum[threadIdx.x >> 6] = s;
    __syncthreads();
    if (threadIdx.x == 0)
        bsums[blockIdx.x] = wsum[0] + wsum[1] + wsum[2] + wsum[3];
}

// ---------------------------------------------------------------------------
// K4: finalize scalars: vq_loss and perplexity (unchanged).
// ---------------------------------------------------------------------------
__global__ __launch_bounds__(256)
void finalize_kernel(const int* __restrict__ counts, const float* __restrict__ bsums,
                     float* __restrict__ out_scalars)
{
    int t = threadIdx.x;
    double ls = 0.0, ps = 0.0;
    for (int i = t; i < 8192; i += 256) {
        ls += (double)bsums[i];
        double avg = (double)counts[i] * (1.0 / 16384.0);
        ps += avg * log(avg + 1e-10);
    }
    #pragma unroll
    for (int off = 32; off; off >>= 1) {
        ls += __shfl_down(ls, off);
        ps += __shfl_down(ps, off);
    }
    __shared__ double l4[4], p4[4];
    if ((t & 63) == 0) { l4[t >> 6] = ls; p4[t >> 6] = ps; }
    __syncthreads();
    if (t == 0) {
        double L = l4[0] + l4[1] + l4[2] + l4[3];
        double P = p4[0] + p4[1] + p4[2] + p4[3];
        out_scalars[0] = (float)(1.25 * L / 8388608.0);
        out_scalars[1] = (float)exp(-P);
    }
}

// ---------------------------------------------------------------------------
// ws layout (bytes):
//   rowkey u64[16384] @ 0       (131072)  (written by collect_rescore)
//   counts int[8192]  @ 131072  (32768)   (zeroed by collect_rescore)
//   bsums  f32[8192]  @ 164096  (32768)
//   esf    f32[8192]  @ 196864  (32768)
// d_out scratch reuse (consumed before gather overwrites):
//   zi8 @ 0 (8MB) | ei8 @ 16777216 (4MB) | tab @ 25165824 (8MB)
// d_out final (floats): quantized[8388608] | vq_loss | perplexity | idx[16384]
// ---------------------------------------------------------------------------
extern "C" void kernel_launch(void* const* d_in, const int* in_sizes, int n_in,
                              void* d_out, int out_size, void* d_ws, size_t ws_size,
                              hipStream_t stream)
{
    const float* z   = (const float*)d_in[0];
    const float* emb = (const float*)d_in[1];

    float* out         = (float*)d_out;
    float* outq        = out;
    float* out_scalars = out + 8388608;
    float* out_idx     = out + 8388610;

    char* ob = (char*)d_out;
    signed char* zi8 = (signed char*)(ob + 0);
    signed char* ei8 = (signed char*)(ob + 16777216);
    unsigned long long* tab = (unsigned long long*)(ob + 25165824);

    char* ws = (char*)d_ws;
    unsigned long long* rowkey = (unsigned long long*)(ws + 0);
    int*   counts = (int*)  (ws + 131072);
    float* bsums  = (float*)(ws + 164096);
    float* esf    = (float*)(ws + 196864);

    prep_kernel<<<2816, 256, 0, stream>>>(z, emb, zi8, ei8, esf);
    screen_kernel<<<dim3(64, 64), 256, 0, stream>>>((const char*)zi8,
                                                    (const char*)ei8, esf, tab);
    collect_rescore_kernel<<<4096, 256, 0, stream>>>(z, emb, esf, tab,
                                                     rowkey, counts);
    gather_loss_kernel<<<8192, 256, 0, stream>>>(z, emb, rowkey, outq, out_idx,
                                                 counts, bsums);
    finalize_kernel<<<1, 256, 0, stream>>>(counts, bsums, out_scalars);
}

// Round 14
// 133.547 us; speedup vs baseline: 1.6182x; 1.1031x over previous
//
#include <hip/hip_runtime.h>
#include <math.h>

typedef int   i32x4 __attribute__((ext_vector_type(4)));

#define NROWS 16384
#define DIMS  512
#define KC    8192
#define QCLIP 4.5f
#define DELTA_INT 1992        // ceil(5.0 / (2*(4.5/127)^2)) grid units
#define IBIAS 16777216        // 2^24 bias so keys are non-negative

__device__ inline unsigned fkey(float v) {
    unsigned u = __float_as_uint(v);
    return (u & 0x80000000u) ? ~u : (u | 0x80000000u);
}
__device__ inline unsigned umin_(unsigned a, unsigned b) { return a < b ? a : b; }
__device__ inline unsigned umax_(unsigned a, unsigned b) { return a > b ? a : b; }

// ---------------------------------------------------------------------------
// K0: fused prep. blocks [0,512): quantize z -> i8 panels; [512,768): emb;
// [768,2816): emb row sum-of-squares (fp64) -> esf (f32) and esq (int grid).
// Packed i8 layout (bytes): p*131072 + s*16384 + c*16, chunk c = f*64+lg*16+rr
// (p = 256-row panel, s = K-step of 64, f = 16-row fragment, lg = k-quarter,
// rr = row-in-fragment). 1KB fragment chunk read at +lane*16 is lane-linear.
// esq[col] = round(esf / (2*s^2)) + 2^24  (s = 4.5/127) -> integer keying:
// ikey = (esq - dot_i32) << 7 | col is exact and overflow-free (< 2^32).
// ---------------------------------------------------------------------------
__global__ __launch_bounds__(256)
void prep_kernel(const float* __restrict__ z, const float* __restrict__ emb,
                 signed char* __restrict__ zi8, signed char* __restrict__ ei8,
                 float* __restrict__ esf, int* __restrict__ esq)
{
    const float QS = 127.0f / QCLIP;
    int b = blockIdx.x, t = threadIdx.x;
    if (b < 768) {
        const float* src;
        signed char* dst;
        int pb;
        if (b < 512) { src = z;   dst = zi8; pb = b; }
        else         { src = emb; dst = ei8; pb = b - 512; }
        int p = pb >> 3, s = pb & 7;
        signed char* dbase = dst + (size_t)p * 131072 + s * 16384;
        #pragma unroll
        for (int q = 0; q < 4; ++q) {
            int c = q * 256 + t;
            int f = c >> 6, lg = (c >> 4) & 3, rr = c & 15;
            int row = p * 256 + f * 16 + rr;
            const float* sp = src + (size_t)row * DIMS + s * 64 + lg * 16;
            float4 v0 = *(const float4*)(sp + 0);
            float4 v1 = *(const float4*)(sp + 4);
            float4 v2 = *(const float4*)(sp + 8);
            float4 v3 = *(const float4*)(sp + 12);
            float vv[16] = {v0.x, v0.y, v0.z, v0.w, v1.x, v1.y, v1.z, v1.w,
                            v2.x, v2.y, v2.z, v2.w, v3.x, v3.y, v3.z, v3.w};
            unsigned w[4];
            #pragma unroll
            for (int k = 0; k < 4; ++k) {
                unsigned r = 0;
                #pragma unroll
                for (int e = 0; e < 4; ++e) {
                    int qv = __float2int_rn(
                        fminf(fmaxf(vv[k * 4 + e] * QS, -127.f), 127.f));
                    r |= (unsigned)(qv & 255) << (e * 8);
                }
                w[k] = r;
            }
            *(i32x4*)(dbase + c * 16) =
                (i32x4){(int)w[0], (int)w[1], (int)w[2], (int)w[3]};
        }
    } else {
        int b2 = b - 768;
        int w = b2 * 4 + (t >> 6);
        int lane = t & 63;
        const float* r = emb + (size_t)w * DIMS;
        float4 v0 = *(const float4*)(r + lane * 4);
        float4 v1 = *(const float4*)(r + 256 + lane * 4);
        double s = (double)v0.x * v0.x + (double)v0.y * v0.y +
                   (double)v0.z * v0.z + (double)v0.w * v0.w +
                   (double)v1.x * v1.x + (double)v1.y * v1.y +
                   (double)v1.z * v1.z + (double)v1.w * v1.w;
        #pragma unroll
        for (int off = 32; off; off >>= 1) s += __shfl_down(s, off);
        if (lane == 0) {
            esf[w] = (float)s;
            const double grid = 2.0 * (QCLIP / 127.0) * (QCLIP / 127.0);
            esq[w] = (int)(s / grid + 0.5) + IBIAS;
        }
    }
}

// ---------------------------------------------------------------------------
// K1: i8 screen GEMM + per-(row, 128-col-block) top-2, INTEGER keys.
// Measured-optimal structure (R13): 256x128 block, 4 waves 2Mx2N, wave tile
// 128x64, mfma_i32_16x16x64_i8, 8 K-steps, dbuf 48KB, 2 blocks/CU.
// Fragment reads lane-linear: conflict-free.
// Epilogue (NEW): key = (esq[col] - dot) << 7 | col_local — 2 VALU ops per
// element (v_sub + v_lshl_or) vs 7 for the fp32 fkey path, and exact.
// tab entry u64 = k1<<32 | k2.
// ---------------------------------------------------------------------------
__global__ __launch_bounds__(256, 2)
void screen_kernel(const char* __restrict__ zq, const char* __restrict__ eq,
                   const int* __restrict__ esq,
                   unsigned long long* __restrict__ tab)
{
    __shared__ char smem[67584];   // dbuf 2x24KB; epilogue table 66KB

    const int t    = threadIdx.x;
    const int lane = t & 63;
    const int wave = t >> 6;
    const int lg   = lane >> 4;
    const int lr   = lane & 15;
    const int wm   = wave >> 1;      // 0..1 row half (128 rows)
    const int wn   = wave & 1;       // 0..1 col half (64 cols)
    const int by   = blockIdx.x;     // col block 0..63 (fast dim)
    const int bx   = blockIdx.y;     // row block 0..63

    const char* gA = zq + (size_t)bx * 131072;
    const char* gB = eq + (size_t)(by >> 1) * 131072 + (by & 1) * 8192;

    i32x4 acc[8][4];
    #pragma unroll
    for (int i = 0; i < 8; ++i)
        #pragma unroll
        for (int j = 0; j < 4; ++j)
            acc[i][j] = (i32x4){0, 0, 0, 0};

    typedef const __attribute__((address_space(1))) unsigned int gq_t;
    typedef __attribute__((address_space(3))) unsigned int lq_t;
    #define STAGE(dstbuf, s)                                                  \
    {                                                                         \
        const char* gsA = gA + (size_t)(s) * 16384;                          \
        const char* gsB = gB + (size_t)(s) * 16384;                          \
        _Pragma("unroll")                                                     \
        for (int k = 0; k < 4; ++k) {                                        \
            int off = k * 4096 + wave * 1024;                                \
            __builtin_amdgcn_global_load_lds(                                 \
                (gq_t*)(gsA + off + lane * 16),                               \
                (lq_t*)((dstbuf) + off), 16, 0, 0);                           \
        }                                                                     \
        _Pragma("unroll")                                                     \
        for (int k = 0; k < 2; ++k) {                                        \
            int off = k * 4096 + wave * 1024;                                \
            __builtin_amdgcn_global_load_lds(                                 \
                (gq_t*)(gsB + off + lane * 16),                               \
                (lq_t*)((dstbuf) + 16384 + off), 16, 0, 0);                   \
        }                                                                     \
    }
    #define COMPUTE(buf)                                                      \
    {                                                                         \
        const char* Ab = (buf) + (wm * 8) * 1024 + lane * 16;                 \
        const char* Bb = (buf) + 16384 + (wn * 4) * 1024 + lane * 16;         \
        i32x4 af[8], bf[4];                                                   \
        _Pragma("unroll")                                                     \
        for (int i = 0; i < 8; ++i) af[i] = *(const i32x4*)(Ab + i * 1024);   \
        _Pragma("unroll")                                                     \
        for (int j = 0; j < 4; ++j) bf[j] = *(const i32x4*)(Bb + j * 1024);   \
        _Pragma("unroll")                                                     \
        for (int i = 0; i < 8; ++i)                                           \
            _Pragma("unroll")                                                 \
            for (int j = 0; j < 4; ++j)                                       \
                acc[i][j] = __builtin_amdgcn_mfma_i32_16x16x64_i8(            \
                    af[i], bf[j], acc[i][j], 0, 0, 0);                        \
    }

    char* p0 = smem;
    char* p1 = smem + 24576;
    STAGE(p0, 0);
    __syncthreads();

    #pragma unroll 1
    for (int s = 0; s < 8; s += 2) {
        STAGE(p1, s + 1);
        COMPUTE(p0);
        __syncthreads();
        if (s + 2 < 8) STAGE(p0, s + 2);
        COMPUTE(p1);
        __syncthreads();
    }

    // ---- epilogue pass 1: per-thread top-2-of-4, integer keys ----
    unsigned long long* mb = (unsigned long long*)smem;  // stride 33/row
    int      esq_j[4];
    unsigned col_j[4];
    #pragma unroll
    for (int j = 0; j < 4; ++j) {
        int cl = wn * 64 + j * 16 + lr;
        esq_j[j] = esq[by * 128 + cl];
        col_j[j] = (unsigned)cl;
    }

    #pragma unroll
    for (int i = 0; i < 8; ++i) {
        #pragma unroll
        for (int r = 0; r < 4; ++r) {
            unsigned k[4];
            #pragma unroll
            for (int j = 0; j < 4; ++j) {
                unsigned iv = (unsigned)(esq_j[j] - acc[i][j][r]);
                k[j] = (iv << 7) | col_j[j];
            }
            unsigned lo1 = umin_(k[0], k[1]), hi1 = umax_(k[0], k[1]);
            unsigned lo2 = umin_(k[2], k[3]), hi2 = umax_(k[2], k[3]);
            unsigned k1 = umin_(lo1, lo2);
            unsigned k2 = umin_(umax_(lo1, lo2), umin_(hi1, hi2));
            int row = wm * 128 + i * 16 + lg * 4 + r;
            mb[row * 33 + wn * 16 + lr] =
                ((unsigned long long)k1 << 32) | k2;
        }
    }
    __syncthreads();

    // ---- epilogue pass 2: one row per thread, merge 32 sorted pairs ----
    {
        unsigned b1 = 0xFFFFFFFFu, b2 = 0xFFFFFFFFu;
        #pragma unroll 4
        for (int q = 0; q < 32; ++q) {
            unsigned long long e = mb[t * 33 + q];
            unsigned e1 = (unsigned)(e >> 32), e2 = (unsigned)e;
            unsigned nb1 = umin_(b1, e1);
            b2 = umin_(umax_(b1, e1), umin_(b2, e2));
            b1 = nb1;
        }
        tab[((size_t)(bx * 256 + t)) * 64 + by] =
            ((unsigned long long)b1 << 32) | b2;
    }
}

// ---------------------------------------------------------------------------
// K2: fused collect + exact fp32 rescore, ZERO global atomics.
// Integer-key threshold: thr = rowmin + DELTA_INT<<7 (same key domain).
// Rescore is exact fp32 (unchanged); rowkey uses float fkey | col.
// ---------------------------------------------------------------------------
__global__ __launch_bounds__(256)
void collect_rescore_kernel(const float* __restrict__ z,
                            const float* __restrict__ emb,
                            const float* __restrict__ esf,
                            const unsigned long long* __restrict__ tab,
                            unsigned long long* __restrict__ rowkey,
                            int* __restrict__ counts)
{
    int t = threadIdx.x, lane = t & 63;
    if (blockIdx.x < 32) counts[blockIdx.x * 256 + t] = 0;
    int row = blockIdx.x * 4 + (t >> 6);

    unsigned long long e = tab[(size_t)row * 64 + lane];
    unsigned k1 = (unsigned)(e >> 32), k2 = (unsigned)e;
    unsigned m = k1;
    #pragma unroll
    for (int mask = 1; mask <= 32; mask <<= 1) {
        unsigned o = (unsigned)__shfl_xor((int)m, mask, 64);
        m = umin_(m, o);
    }
    unsigned thr = m + ((unsigned)DELTA_INT << 7);
    unsigned long long m1 = __ballot(k1 <= thr);
    unsigned long long m2 = __ballot(k2 <= thr);

    const float4* zr = (const float4*)(z + (size_t)row * DIMS + lane * 8);
    float4 a0 = zr[0], a1 = zr[1];

    unsigned long long best = ~0ull;
    while (m1 | m2) {
        int src;
        unsigned kk;
        if (m1) {
            src = __ffsll((long long)m1) - 1;
            m1 &= m1 - 1;
            kk = (unsigned)__shfl((int)k1, src, 64);
        } else {
            src = __ffsll((long long)m2) - 1;
            m2 &= m2 - 1;
            kk = (unsigned)__shfl((int)k2, src, 64);
        }
        int col = src * 128 + (int)(kk & 127u);

        const float4* er = (const float4*)(emb + (size_t)col * DIMS + lane * 8);
        float4 b0 = er[0], b1v = er[1];
        float s = a0.x * b0.x;
        s = fmaf(a0.y, b0.y, s); s = fmaf(a0.z, b0.z, s);
        s = fmaf(a0.w, b0.w, s); s = fmaf(a1.x, b1v.x, s);
        s = fmaf(a1.y, b1v.y, s); s = fmaf(a1.z, b1v.z, s);
        s = fmaf(a1.w, b1v.w, s);
        #pragma unroll
        for (int mask = 32; mask; mask >>= 1) s += __shfl_xor(s, mask);
        float v = fmaf(-2.f, s, esf[col]);
        unsigned long long key =
            ((unsigned long long)fkey(v) << 32) | (unsigned)col;
        best = key < best ? key : best;
    }
    if (lane == 0) rowkey[row] = best;
}

// ---------------------------------------------------------------------------
// K3: gather + loss partials + index output + histogram (unchanged).
// ---------------------------------------------------------------------------
__global__ __launch_bounds__(256)
void gather_loss_kernel(const float* __restrict__ z, const float* __restrict__ emb,
                        const unsigned long long* __restrict__ rowkey,
                        float* __restrict__ outq, float* __restrict__ out_idx_f,
                        int* __restrict__ counts, float* __restrict__ bsums)
{
    int gid = blockIdx.x * 256 + threadIdx.x;
    int row = gid >> 7;
    int c4  = (gid & 127) << 2;
    int idx = (int)(rowkey[row] & 0xFFFFFFFFull);
    if ((gid & 127) == 0) {
        out_idx_f[row] = (float)idx;
        atomicAdd(&counts[idx], 1);
    }
    float4 e  = *(const float4*)&emb[(size_t)idx * DIMS + c4];
    float4 zv = *(const float4*)&z[(size_t)row * DIMS + c4];
    *(float4*)&outq[(size_t)row * DIMS + c4] = e;
    float dx = e.x - zv.x, dy = e.y - zv.y, dz = e.z - zv.z, dw = e.w - zv.w;
    float s = dx * dx + dy * dy + dz * dz + dw * dw;
    #pragma unroll
    for (int off = 32; off; off >>= 1) s += __shfl_down(s, off);
    __shared__ float wsum[4];
    if ((threadIdx.x & 63) == 0) wsum[threadIdx.x >> 6] = s;
    __syncthreads();
    if (threadIdx.x == 0)
        bsums[blockIdx.x] = wsum[0] + wsum[1] + wsum[2] + wsum[3];
}

// ---------------------------------------------------------------------------
// K4: finalize scalars: vq_loss and perplexity (unchanged).
// ---------------------------------------------------------------------------
__global__ __launch_bounds__(256)
void finalize_kernel(const int* __restrict__ counts, const float* __restrict__ bsums,
                     float* __restrict__ out_scalars)
{
    int t = threadIdx.x;
    double ls = 0.0, ps = 0.0;
    for (int i = t; i < 8192; i += 256) {
        ls += (double)bsums[i];
        double avg = (double)counts[i] * (1.0 / 16384.0);
        ps += avg * log(avg + 1e-10);
    }
    #pragma unroll
    for (int off = 32; off; off >>= 1) {
        ls += __shfl_down(ls, off);
        ps += __shfl_down(ps, off);
    }
    __shared__ double l4[4], p4[4];
    if ((t & 63) == 0) { l4[t >> 6] = ls; p4[t >> 6] = ps; }
    __syncthreads();
    if (t == 0) {
        double L = l4[0] + l4[1] + l4[2] + l4[3];
        double P = p4[0] + p4[1] + p4[2] + p4[3];
        out_scalars[0] = (float)(1.25 * L / 8388608.0);
        out_scalars[1] = (float)exp(-P);
    }
}

// ---------------------------------------------------------------------------
// ws layout (bytes):
//   rowkey u64[16384] @ 0       (131072)  (written by collect_rescore)
//   counts int[8192]  @ 131072  (32768)   (zeroed by collect_rescore)
//   bsums  f32[8192]  @ 164096  (32768)
//   esf    f32[8192]  @ 196864  (32768)
//   esq    i32[8192]  @ 229632  (32768)
// d_out scratch reuse (consumed before gather overwrites):
//   zi8 @ 0 (8MB) | ei8 @ 16777216 (4MB) | tab @ 25165824 (8MB)
// d_out final (floats): quantized[8388608] | vq_loss | perplexity | idx[16384]
// ---------------------------------------------------------------------------
extern "C" void kernel_launch(void* const* d_in, const int* in_sizes, int n_in,
                              void* d_out, int out_size, void* d_ws, size_t ws_size,
                              hipStream_t stream)
{
    const float* z   = (const float*)d_in[0];
    const float* emb = (const float*)d_in[1];

    float* out         = (float*)d_out;
    float* outq        = out;
    float* out_scalars = out + 8388608;
    float* out_idx     = out + 8388610;

    char* ob = (char*)d_out;
    signed char* zi8 = (signed char*)(ob + 0);
    signed char* ei8 = (signed char*)(ob + 16777216);
    unsigned long long* tab = (unsigned long long*)(ob + 25165824);

    char* ws = (char*)d_ws;
    unsigned long long* rowkey = (unsigned long long*)(ws + 0);
    int*   counts = (int*)  (ws + 131072);
    float* bsums  = (float*)(ws + 164096);
    float* esf    = (float*)(ws + 196864);
    int*   esq    = (int*)  (ws + 229632);

    prep_kernel<<<2816, 256, 0, stream>>>(z, emb, zi8, ei8, esf, esq);
    screen_kernel<<<dim3(64, 64), 256, 0, stream>>>((const char*)zi8,
                                                    (const char*)ei8, esq, tab);
    collect_rescore_kernel<<<4096, 256, 0, stream>>>(z, emb, esf, tab,
                                                     rowkey, counts);
    gather_loss_kernel<<<8192, 256, 0, stream>>>(z, emb, rowkey, outq, out_idx,
                                                 counts, bsums);
    finalize_kernel<<<1, 256, 0, stream>>>(counts, bsums, out_scalars);
}

// Round 15
// 132.204 us; speedup vs baseline: 1.6346x; 1.0102x over previous
//
#include <hip/hip_runtime.h>
#include <math.h>

typedef int   i32x4 __attribute__((ext_vector_type(4)));

#define NROWS 16384
#define DIMS  512
#define KC    8192
#define QCLIP 4.5f
#define DELTA_INT 1992        // ceil(5.0 / (2*(4.5/127)^2)) grid units
#define IBIAS 16777216        // 2^24 bias so keys are non-negative

__device__ inline unsigned fkey(float v) {
    unsigned u = __float_as_uint(v);
    return (u & 0x80000000u) ? ~u : (u | 0x80000000u);
}
__device__ inline unsigned umin_(unsigned a, unsigned b) { return a < b ? a : b; }
__device__ inline unsigned umax_(unsigned a, unsigned b) { return a > b ? a : b; }

// ---------------------------------------------------------------------------
// K0: fused prep. blocks [0,512): quantize z -> i8 panels; [512,768): emb;
// [768,2816): emb row sum-of-squares (fp64) -> esf (f32) and esq (int grid).
// Packed i8 layout (bytes): p*131072 + s*16384 + c*16, chunk c = f*64+lg*16+rr
// (p = 256-row panel, s = K-step of 64, f = 16-row fragment, lg = k-quarter,
// rr = row-in-fragment). 1KB fragment chunk read at +lane*16 is lane-linear.
// esq[col] = round(esf / (2*s^2)) + 2^24  (s = 4.5/127) -> integer keying:
// ikey = (esq - dot_i32) << 7 | col is exact and overflow-free (< 2^32).
// ---------------------------------------------------------------------------
__global__ __launch_bounds__(256)
void prep_kernel(const float* __restrict__ z, const float* __restrict__ emb,
                 signed char* __restrict__ zi8, signed char* __restrict__ ei8,
                 float* __restrict__ esf, int* __restrict__ esq)
{
    const float QS = 127.0f / QCLIP;
    int b = blockIdx.x, t = threadIdx.x;
    if (b < 768) {
        const float* src;
        signed char* dst;
        int pb;
        if (b < 512) { src = z;   dst = zi8; pb = b; }
        else         { src = emb; dst = ei8; pb = b - 512; }
        int p = pb >> 3, s = pb & 7;
        signed char* dbase = dst + (size_t)p * 131072 + s * 16384;
        #pragma unroll
        for (int q = 0; q < 4; ++q) {
            int c = q * 256 + t;
            int f = c >> 6, lg = (c >> 4) & 3, rr = c & 15;
            int row = p * 256 + f * 16 + rr;
            const float* sp = src + (size_t)row * DIMS + s * 64 + lg * 16;
            float4 v0 = *(const float4*)(sp + 0);
            float4 v1 = *(const float4*)(sp + 4);
            float4 v2 = *(const float4*)(sp + 8);
            float4 v3 = *(const float4*)(sp + 12);
            float vv[16] = {v0.x, v0.y, v0.z, v0.w, v1.x, v1.y, v1.z, v1.w,
                            v2.x, v2.y, v2.z, v2.w, v3.x, v3.y, v3.z, v3.w};
            unsigned w[4];
            #pragma unroll
            for (int k = 0; k < 4; ++k) {
                unsigned r = 0;
                #pragma unroll
                for (int e = 0; e < 4; ++e) {
                    int qv = __float2int_rn(
                        fminf(fmaxf(vv[k * 4 + e] * QS, -127.f), 127.f));
                    r |= (unsigned)(qv & 255) << (e * 8);
                }
                w[k] = r;
            }
            *(i32x4*)(dbase + c * 16) =
                (i32x4){(int)w[0], (int)w[1], (int)w[2], (int)w[3]};
        }
    } else {
        int b2 = b - 768;
        int w = b2 * 4 + (t >> 6);
        int lane = t & 63;
        const float* r = emb + (size_t)w * DIMS;
        float4 v0 = *(const float4*)(r + lane * 4);
        float4 v1 = *(const float4*)(r + 256 + lane * 4);
        double s = (double)v0.x * v0.x + (double)v0.y * v0.y +
                   (double)v0.z * v0.z + (double)v0.w * v0.w +
                   (double)v1.x * v1.x + (double)v1.y * v1.y +
                   (double)v1.z * v1.z + (double)v1.w * v1.w;
        #pragma unroll
        for (int off = 32; off; off >>= 1) s += __shfl_down(s, off);
        if (lane == 0) {
            esf[w] = (float)s;
            const double grid = 2.0 * (QCLIP / 127.0) * (QCLIP / 127.0);
            esq[w] = (int)(s / grid + 0.5) + IBIAS;
        }
    }
}

// ---------------------------------------------------------------------------
// K1: i8 screen GEMM + per-(row, 128-col-block) top-2, INTEGER keys.
// R15 change: GRID TRANSPOSED (bx = row block on the FAST axis). Co-resident
// block pairs on a CU (~one grid-wave apart in dispatch) now share the SAME
// A panel instead of the B panel -> per-CU unique staged bytes per step drop
// 48KB -> 32KB if the shared stage lines hit L1/L2-hot paths (staging is the
// largest per-step pipe at ~857 cyc). Everything else identical to R14's
// measured optimum (256x128 block, 4 waves 2Mx2N, wave tile 128x64,
// mfma_i32_16x16x64_i8, 8 K-steps, dbuf 48KB, 2 blocks/CU, integer keys).
// ---------------------------------------------------------------------------
__global__ __launch_bounds__(256, 2)
void screen_kernel(const char* __restrict__ zq, const char* __restrict__ eq,
                   const int* __restrict__ esq,
                   unsigned long long* __restrict__ tab)
{
    __shared__ char smem[67584];   // dbuf 2x24KB; epilogue table 66KB

    const int t    = threadIdx.x;
    const int lane = t & 63;
    const int wave = t >> 6;
    const int lg   = lane >> 4;
    const int lr   = lane & 15;
    const int wm   = wave >> 1;      // 0..1 row half (128 rows)
    const int wn   = wave & 1;       // 0..1 col half (64 cols)
    const int bx   = blockIdx.x;     // row block 0..63 (FAST dim — R15)
    const int by   = blockIdx.y;     // col block 0..63 (slow dim)

    const char* gA = zq + (size_t)bx * 131072;
    const char* gB = eq + (size_t)(by >> 1) * 131072 + (by & 1) * 8192;

    i32x4 acc[8][4];
    #pragma unroll
    for (int i = 0; i < 8; ++i)
        #pragma unroll
        for (int j = 0; j < 4; ++j)
            acc[i][j] = (i32x4){0, 0, 0, 0};

    typedef const __attribute__((address_space(1))) unsigned int gq_t;
    typedef __attribute__((address_space(3))) unsigned int lq_t;
    #define STAGE(dstbuf, s)                                                  \
    {                                                                         \
        const char* gsA = gA + (size_t)(s) * 16384;                          \
        const char* gsB = gB + (size_t)(s) * 16384;                          \
        _Pragma("unroll")                                                     \
        for (int k = 0; k < 4; ++k) {                                        \
            int off = k * 4096 + wave * 1024;                                \
            __builtin_amdgcn_global_load_lds(                                 \
                (gq_t*)(gsA + off + lane * 16),                               \
                (lq_t*)((dstbuf) + off), 16, 0, 0);                           \
        }                                                                     \
        _Pragma("unroll")                                                     \
        for (int k = 0; k < 2; ++k) {                                        \
            int off = k * 4096 + wave * 1024;                                \
            __builtin_amdgcn_global_load_lds(                                 \
                (gq_t*)(gsB + off + lane * 16),                               \
                (lq_t*)((dstbuf) + 16384 + off), 16, 0, 0);                   \
        }                                                                     \
    }
    #define COMPUTE(buf)                                                      \
    {                                                                         \
        const char* Ab = (buf) + (wm * 8) * 1024 + lane * 16;                 \
        const char* Bb = (buf) + 16384 + (wn * 4) * 1024 + lane * 16;         \
        i32x4 af[8], bf[4];                                                   \
        _Pragma("unroll")                                                     \
        for (int i = 0; i < 8; ++i) af[i] = *(const i32x4*)(Ab + i * 1024);   \
        _Pragma("unroll")                                                     \
        for (int j = 0; j < 4; ++j) bf[j] = *(const i32x4*)(Bb + j * 1024);   \
        _Pragma("unroll")                                                     \
        for (int i = 0; i < 8; ++i)                                           \
            _Pragma("unroll")                                                 \
            for (int j = 0; j < 4; ++j)                                       \
                acc[i][j] = __builtin_amdgcn_mfma_i32_16x16x64_i8(            \
                    af[i], bf[j], acc[i][j], 0, 0, 0);                        \
    }

    char* p0 = smem;
    char* p1 = smem + 24576;
    STAGE(p0, 0);
    __syncthreads();

    #pragma unroll 1
    for (int s = 0; s < 8; s += 2) {
        STAGE(p1, s + 1);
        COMPUTE(p0);
        __syncthreads();
        if (s + 2 < 8) STAGE(p0, s + 2);
        COMPUTE(p1);
        __syncthreads();
    }

    // ---- epilogue pass 1: per-thread top-2-of-4, integer keys ----
    unsigned long long* mb = (unsigned long long*)smem;  // stride 33/row
    int      esq_j[4];
    unsigned col_j[4];
    #pragma unroll
    for (int j = 0; j < 4; ++j) {
        int cl = wn * 64 + j * 16 + lr;
        esq_j[j] = esq[by * 128 + cl];
        col_j[j] = (unsigned)cl;
    }

    #pragma unroll
    for (int i = 0; i < 8; ++i) {
        #pragma unroll
        for (int r = 0; r < 4; ++r) {
            unsigned k[4];
            #pragma unroll
            for (int j = 0; j < 4; ++j) {
                unsigned iv = (unsigned)(esq_j[j] - acc[i][j][r]);
                k[j] = (iv << 7) | col_j[j];
            }
            unsigned lo1 = umin_(k[0], k[1]), hi1 = umax_(k[0], k[1]);
            unsigned lo2 = umin_(k[2], k[3]), hi2 = umax_(k[2], k[3]);
            unsigned k1 = umin_(lo1, lo2);
            unsigned k2 = umin_(umax_(lo1, lo2), umin_(hi1, hi2));
            int row = wm * 128 + i * 16 + lg * 4 + r;
            mb[row * 33 + wn * 16 + lr] =
                ((unsigned long long)k1 << 32) | k2;
        }
    }
    __syncthreads();

    // ---- epilogue pass 2: one row per thread, merge 32 sorted pairs ----
    {
        unsigned b1 = 0xFFFFFFFFu, b2 = 0xFFFFFFFFu;
        #pragma unroll 4
        for (int q = 0; q < 32; ++q) {
            unsigned long long e = mb[t * 33 + q];
            unsigned e1 = (unsigned)(e >> 32), e2 = (unsigned)e;
            unsigned nb1 = umin_(b1, e1);
            b2 = umin_(umax_(b1, e1), umin_(b2, e2));
            b1 = nb1;
        }
        tab[((size_t)(bx * 256 + t)) * 64 + by] =
            ((unsigned long long)b1 << 32) | b2;
    }
}

// ---------------------------------------------------------------------------
// K2: fused collect + exact fp32 rescore, ZERO global atomics (unchanged).
// Integer-key threshold: thr = rowmin + DELTA_INT<<7 (same key domain).
// ---------------------------------------------------------------------------
__global__ __launch_bounds__(256)
void collect_rescore_kernel(const float* __restrict__ z,
                            const float* __restrict__ emb,
                            const float* __restrict__ esf,
                            const unsigned long long* __restrict__ tab,
                            unsigned long long* __restrict__ rowkey,
                            int* __restrict__ counts)
{
    int t = threadIdx.x, lane = t & 63;
    if (blockIdx.x < 32) counts[blockIdx.x * 256 + t] = 0;
    int row = blockIdx.x * 4 + (t >> 6);

    unsigned long long e = tab[(size_t)row * 64 + lane];
    unsigned k1 = (unsigned)(e >> 32), k2 = (unsigned)e;
    unsigned m = k1;
    #pragma unroll
    for (int mask = 1; mask <= 32; mask <<= 1) {
        unsigned o = (unsigned)__shfl_xor((int)m, mask, 64);
        m = umin_(m, o);
    }
    unsigned thr = m + ((unsigned)DELTA_INT << 7);
    unsigned long long m1 = __ballot(k1 <= thr);
    unsigned long long m2 = __ballot(k2 <= thr);

    const float4* zr = (const float4*)(z + (size_t)row * DIMS + lane * 8);
    float4 a0 = zr[0], a1 = zr[1];

    unsigned long long best = ~0ull;
    while (m1 | m2) {
        int src;
        unsigned kk;
        if (m1) {
            src = __ffsll((long long)m1) - 1;
            m1 &= m1 - 1;
            kk = (unsigned)__shfl((int)k1, src, 64);
        } else {
            src = __ffsll((long long)m2) - 1;
            m2 &= m2 - 1;
            kk = (unsigned)__shfl((int)k2, src, 64);
        }
        int col = src * 128 + (int)(kk & 127u);

        const float4* er = (const float4*)(emb + (size_t)col * DIMS + lane * 8);
        float4 b0 = er[0], b1v = er[1];
        float s = a0.x * b0.x;
        s = fmaf(a0.y, b0.y, s); s = fmaf(a0.z, b0.z, s);
        s = fmaf(a0.w, b0.w, s); s = fmaf(a1.x, b1v.x, s);
        s = fmaf(a1.y, b1v.y, s); s = fmaf(a1.z, b1v.z, s);
        s = fmaf(a1.w, b1v.w, s);
        #pragma unroll
        for (int mask = 32; mask; mask >>= 1) s += __shfl_xor(s, mask);
        float v = fmaf(-2.f, s, esf[col]);
        unsigned long long key =
            ((unsigned long long)fkey(v) << 32) | (unsigned)col;
        best = key < best ? key : best;
    }
    if (lane == 0) rowkey[row] = best;
}

// ---------------------------------------------------------------------------
// K3: gather + loss partials + index output + histogram (unchanged).
// ---------------------------------------------------------------------------
__global__ __launch_bounds__(256)
void gather_loss_kernel(const float* __restrict__ z, const float* __restrict__ emb,
                        const unsigned long long* __restrict__ rowkey,
                        float* __restrict__ outq, float* __restrict__ out_idx_f,
                        int* __restrict__ counts, float* __restrict__ bsums)
{
    int gid = blockIdx.x * 256 + threadIdx.x;
    int row = gid >> 7;
    int c4  = (gid & 127) << 2;
    int idx = (int)(rowkey[row] & 0xFFFFFFFFull);
    if ((gid & 127) == 0) {
        out_idx_f[row] = (float)idx;
        atomicAdd(&counts[idx], 1);
    }
    float4 e  = *(const float4*)&emb[(size_t)idx * DIMS + c4];
    float4 zv = *(const float4*)&z[(size_t)row * DIMS + c4];
    *(float4*)&outq[(size_t)row * DIMS + c4] = e;
    float dx = e.x - zv.x, dy = e.y - zv.y, dz = e.z - zv.z, dw = e.w - zv.w;
    float s = dx * dx + dy * dy + dz * dz + dw * dw;
    #pragma unroll
    for (int off = 32; off; off >>= 1) s += __shfl_down(s, off);
    __shared__ float wsum[4];
    if ((threadIdx.x & 63) == 0) wsum[threadIdx.x >> 6] = s;
    __syncthreads();
    if (threadIdx.x == 0)
        bsums[blockIdx.x] = wsum[0] + wsum[1] + wsum[2] + wsum[3];
}

// ---------------------------------------------------------------------------
// K4: finalize scalars: vq_loss and perplexity (unchanged).
// ---------------------------------------------------------------------------
__global__ __launch_bounds__(256)
void finalize_kernel(const int* __restrict__ counts, const float* __restrict__ bsums,
                     float* __restrict__ out_scalars)
{
    int t = threadIdx.x;
    double ls = 0.0, ps = 0.0;
    for (int i = t; i < 8192; i += 256) {
        ls += (double)bsums[i];
        double avg = (double)counts[i] * (1.0 / 16384.0);
        ps += avg * log(avg + 1e-10);
    }
    #pragma unroll
    for (int off = 32; off; off >>= 1) {
        ls += __shfl_down(ls, off);
        ps += __shfl_down(ps, off);
    }
    __shared__ double l4[4], p4[4];
    if ((t & 63) == 0) { l4[t >> 6] = ls; p4[t >> 6] = ps; }
    __syncthreads();
    if (t == 0) {
        double L = l4[0] + l4[1] + l4[2] + l4[3];
        double P = p4[0] + p4[1] + p4[2] + p4[3];
        out_scalars[0] = (float)(1.25 * L / 8388608.0);
        out_scalars[1] = (float)exp(-P);
    }
}

// ---------------------------------------------------------------------------
// ws layout (bytes):
//   rowkey u64[16384] @ 0       (131072)  (written by collect_rescore)
//   counts int[8192]  @ 131072  (32768)   (zeroed by collect_rescore)
//   bsums  f32[8192]  @ 164096  (32768)
//   esf    f32[8192]  @ 196864  (32768)
//   esq    i32[8192]  @ 229632  (32768)
// d_out scratch reuse (consumed before gather overwrites):
//   zi8 @ 0 (8MB) | ei8 @ 16777216 (4MB) | tab @ 25165824 (8MB)
// d_out final (floats): quantized[8388608] | vq_loss | perplexity | idx[16384]
// ---------------------------------------------------------------------------
extern "C" void kernel_launch(void* const* d_in, const int* in_sizes, int n_in,
                              void* d_out, int out_size, void* d_ws, size_t ws_size,
                              hipStream_t stream)
{
    const float* z   = (const float*)d_in[0];
    const float* emb = (const float*)d_in[1];

    float* out         = (float*)d_out;
    float* outq        = out;
    float* out_scalars = out + 8388608;
    float* out_idx     = out + 8388610;

    char* ob = (char*)d_out;
    signed char* zi8 = (signed char*)(ob + 0);
    signed char* ei8 = (signed char*)(ob + 16777216);
    unsigned long long* tab = (unsigned long long*)(ob + 25165824);

    char* ws = (char*)d_ws;
    unsigned long long* rowkey = (unsigned long long*)(ws + 0);
    int*   counts = (int*)  (ws + 131072);
    float* bsums  = (float*)(ws + 164096);
    float* esf    = (float*)(ws + 196864);
    int*   esq    = (int*)  (ws + 229632);

    prep_kernel<<<2816, 256, 0, stream>>>(z, emb, zi8, ei8, esf, esq);
    screen_kernel<<<dim3(64, 64), 256, 0, stream>>>((const char*)zi8,
                                                    (const char*)ei8, esq, tab);
    collect_rescore_kernel<<<4096, 256, 0, stream>>>(z, emb, esf, tab,
                                                     rowkey, counts);
    gather_loss_kernel<<<8192, 256, 0, stream>>>(z, emb, rowkey, outq, out_idx,
                                                 counts, bsums);
    finalize_kernel<<<1, 256, 0, stream>>>(counts, bsums, out_scalars);
}

// Round 16
// 129.301 us; speedup vs baseline: 1.6713x; 1.0224x over previous
//
#include <hip/hip_runtime.h>
#include <math.h>

typedef int   i32x4 __attribute__((ext_vector_type(4)));

#define NROWS 16384
#define DIMS  512
#define KC    8192
#define QCLIP 4.5f
#define DELTA_INT 1992        // ceil(5.0 / (2*(4.5/127)^2)) grid units
#define IBIAS 16777216        // 2^24 bias so keys are non-negative

__device__ inline unsigned fkey(float v) {
    unsigned u = __float_as_uint(v);
    return (u & 0x80000000u) ? ~u : (u | 0x80000000u);
}
__device__ inline unsigned umin_(unsigned a, unsigned b) { return a < b ? a : b; }
__device__ inline unsigned umax_(unsigned a, unsigned b) { return a > b ? a : b; }

// ---------------------------------------------------------------------------
// K0: fused prep. blocks [0,512): quantize z -> i8 panels; [512,768): emb
// (blocks [0,32) also zero the histogram counts — kernel boundary orders
// this before the fused rescore's atomics); [768,2816): emb row
// sum-of-squares (fp64) -> esf (f32) and esq (int grid).
// Packed i8 layout (bytes): p*131072 + s*16384 + c*16, chunk c = f*64+lg*16+rr
// (p = 256-row panel, s = K-step of 64, f = 16-row fragment, lg = k-quarter,
// rr = row-in-fragment). 1KB fragment chunk read at +lane*16 is lane-linear.
// esq[col] = round(esf / (2*s^2)) + 2^24 -> integer keying in the screen.
// ---------------------------------------------------------------------------
__global__ __launch_bounds__(256)
void prep_kernel(const float* __restrict__ z, const float* __restrict__ emb,
                 signed char* __restrict__ zi8, signed char* __restrict__ ei8,
                 float* __restrict__ esf, int* __restrict__ esq,
                 int* __restrict__ counts)
{
    const float QS = 127.0f / QCLIP;
    int b = blockIdx.x, t = threadIdx.x;
    if (b < 768) {
        if (b < 32) counts[b * 256 + t] = 0;
        const float* src;
        signed char* dst;
        int pb;
        if (b < 512) { src = z;   dst = zi8; pb = b; }
        else         { src = emb; dst = ei8; pb = b - 512; }
        int p = pb >> 3, s = pb & 7;
        signed char* dbase = dst + (size_t)p * 131072 + s * 16384;
        #pragma unroll
        for (int q = 0; q < 4; ++q) {
            int c = q * 256 + t;
            int f = c >> 6, lg = (c >> 4) & 3, rr = c & 15;
            int row = p * 256 + f * 16 + rr;
            const float* sp = src + (size_t)row * DIMS + s * 64 + lg * 16;
            float4 v0 = *(const float4*)(sp + 0);
            float4 v1 = *(const float4*)(sp + 4);
            float4 v2 = *(const float4*)(sp + 8);
            float4 v3 = *(const float4*)(sp + 12);
            float vv[16] = {v0.x, v0.y, v0.z, v0.w, v1.x, v1.y, v1.z, v1.w,
                            v2.x, v2.y, v2.z, v2.w, v3.x, v3.y, v3.z, v3.w};
            unsigned w[4];
            #pragma unroll
            for (int k = 0; k < 4; ++k) {
                unsigned r = 0;
                #pragma unroll
                for (int e = 0; e < 4; ++e) {
                    int qv = __float2int_rn(
                        fminf(fmaxf(vv[k * 4 + e] * QS, -127.f), 127.f));
                    r |= (unsigned)(qv & 255) << (e * 8);
                }
                w[k] = r;
            }
            *(i32x4*)(dbase + c * 16) =
                (i32x4){(int)w[0], (int)w[1], (int)w[2], (int)w[3]};
        }
    } else {
        int b2 = b - 768;
        int w = b2 * 4 + (t >> 6);
        int lane = t & 63;
        const float* r = emb + (size_t)w * DIMS;
        float4 v0 = *(const float4*)(r + lane * 4);
        float4 v1 = *(const float4*)(r + 256 + lane * 4);
        double s = (double)v0.x * v0.x + (double)v0.y * v0.y +
                   (double)v0.z * v0.z + (double)v0.w * v0.w +
                   (double)v1.x * v1.x + (double)v1.y * v1.y +
                   (double)v1.z * v1.z + (double)v1.w * v1.w;
        #pragma unroll
        for (int off = 32; off; off >>= 1) s += __shfl_down(s, off);
        if (lane == 0) {
            esf[w] = (float)s;
            const double grid = 2.0 * (QCLIP / 127.0) * (QCLIP / 127.0);
            esq[w] = (int)(s / grid + 0.5) + IBIAS;
        }
    }
}

// ---------------------------------------------------------------------------
// K1: i8 screen GEMM + per-(row, 128-col-block) top-2, INTEGER keys.
// Measured optimum (R14/R15): 256x128 block, 4 waves 2Mx2N, wave tile
// 128x64, mfma_i32_16x16x64_i8, 8 K-steps, dbuf 48KB, 2 blocks/CU,
// bx on the fast grid axis (co-resident pairs share the A panel: FETCH
// -40%, R15). Fragment reads lane-linear: conflict-free.
// Epilogue: key = (esq[col] - dot) << 7 | col_local (2 VALU ops, exact).
// tab entry u64 = k1<<32 | k2.
// ---------------------------------------------------------------------------
__global__ __launch_bounds__(256, 2)
void screen_kernel(const char* __restrict__ zq, const char* __restrict__ eq,
                   const int* __restrict__ esq,
                   unsigned long long* __restrict__ tab)
{
    __shared__ char smem[67584];   // dbuf 2x24KB; epilogue table 66KB

    const int t    = threadIdx.x;
    const int lane = t & 63;
    const int wave = t >> 6;
    const int lg   = lane >> 4;
    const int lr   = lane & 15;
    const int wm   = wave >> 1;      // 0..1 row half (128 rows)
    const int wn   = wave & 1;       // 0..1 col half (64 cols)
    const int bx   = blockIdx.x;     // row block 0..63 (FAST dim)
    const int by   = blockIdx.y;     // col block 0..63 (slow dim)

    const char* gA = zq + (size_t)bx * 131072;
    const char* gB = eq + (size_t)(by >> 1) * 131072 + (by & 1) * 8192;

    i32x4 acc[8][4];
    #pragma unroll
    for (int i = 0; i < 8; ++i)
        #pragma unroll
        for (int j = 0; j < 4; ++j)
            acc[i][j] = (i32x4){0, 0, 0, 0};

    typedef const __attribute__((address_space(1))) unsigned int gq_t;
    typedef __attribute__((address_space(3))) unsigned int lq_t;
    #define STAGE(dstbuf, s)                                                  \
    {                                                                         \
        const char* gsA = gA + (size_t)(s) * 16384;                          \
        const char* gsB = gB + (size_t)(s) * 16384;                          \
        _Pragma("unroll")                                                     \
        for (int k = 0; k < 4; ++k) {                                        \
            int off = k * 4096 + wave * 1024;                                \
            __builtin_amdgcn_global_load_lds(                                 \
                (gq_t*)(gsA + off + lane * 16),                               \
                (lq_t*)((dstbuf) + off), 16, 0, 0);                           \
        }                                                                     \
        _Pragma("unroll")                                                     \
        for (int k = 0; k < 2; ++k) {                                        \
            int off = k * 4096 + wave * 1024;                                \
            __builtin_amdgcn_global_load_lds(                                 \
                (gq_t*)(gsB + off + lane * 16),                               \
                (lq_t*)((dstbuf) + 16384 + off), 16, 0, 0);                   \
        }                                                                     \
    }
    #define COMPUTE(buf)                                                      \
    {                                                                         \
        const char* Ab = (buf) + (wm * 8) * 1024 + lane * 16;                 \
        const char* Bb = (buf) + 16384 + (wn * 4) * 1024 + lane * 16;         \
        i32x4 af[8], bf[4];                                                   \
        _Pragma("unroll")                                                     \
        for (int i = 0; i < 8; ++i) af[i] = *(const i32x4*)(Ab + i * 1024);   \
        _Pragma("unroll")                                                     \
        for (int j = 0; j < 4; ++j) bf[j] = *(const i32x4*)(Bb + j * 1024);   \
        _Pragma("unroll")                                                     \
        for (int i = 0; i < 8; ++i)                                           \
            _Pragma("unroll")                                                 \
            for (int j = 0; j < 4; ++j)                                       \
                acc[i][j] = __builtin_amdgcn_mfma_i32_16x16x64_i8(            \
                    af[i], bf[j], acc[i][j], 0, 0, 0);                        \
    }

    char* p0 = smem;
    char* p1 = smem + 24576;
    STAGE(p0, 0);
    __syncthreads();

    #pragma unroll 1
    for (int s = 0; s < 8; s += 2) {
        STAGE(p1, s + 1);
        COMPUTE(p0);
        __syncthreads();
        if (s + 2 < 8) STAGE(p0, s + 2);
        COMPUTE(p1);
        __syncthreads();
    }

    // ---- epilogue pass 1: per-thread top-2-of-4, integer keys ----
    unsigned long long* mb = (unsigned long long*)smem;  // stride 33/row
    int      esq_j[4];
    unsigned col_j[4];
    #pragma unroll
    for (int j = 0; j < 4; ++j) {
        int cl = wn * 64 + j * 16 + lr;
        esq_j[j] = esq[by * 128 + cl];
        col_j[j] = (unsigned)cl;
    }

    #pragma unroll
    for (int i = 0; i < 8; ++i) {
        #pragma unroll
        for (int r = 0; r < 4; ++r) {
            unsigned k[4];
            #pragma unroll
            for (int j = 0; j < 4; ++j) {
                unsigned iv = (unsigned)(esq_j[j] - acc[i][j][r]);
                k[j] = (iv << 7) | col_j[j];
            }
            unsigned lo1 = umin_(k[0], k[1]), hi1 = umax_(k[0], k[1]);
            unsigned lo2 = umin_(k[2], k[3]), hi2 = umax_(k[2], k[3]);
            unsigned k1 = umin_(lo1, lo2);
            unsigned k2 = umin_(umax_(lo1, lo2), umin_(hi1, hi2));
            int row = wm * 128 + i * 16 + lg * 4 + r;
            mb[row * 33 + wn * 16 + lr] =
                ((unsigned long long)k1 << 32) | k2;
        }
    }
    __syncthreads();

    // ---- epilogue pass 2: one row per thread, merge 32 sorted pairs ----
    {
        unsigned b1 = 0xFFFFFFFFu, b2 = 0xFFFFFFFFu;
        #pragma unroll 4
        for (int q = 0; q < 32; ++q) {
            unsigned long long e = mb[t * 33 + q];
            unsigned e1 = (unsigned)(e >> 32), e2 = (unsigned)e;
            unsigned nb1 = umin_(b1, e1);
            b2 = umin_(umax_(b1, e1), umin_(b2, e2));
            b1 = nb1;
        }
        tab[((size_t)(bx * 256 + t)) * 64 + by] =
            ((unsigned long long)b1 << 32) | b2;
    }
}

// ---------------------------------------------------------------------------
// K2: fused collect + exact fp32 rescore + gather + loss + histogram.
// One wave per row (4 rows/block), zero single-address atomics:
//   1. shuffle-min over 64 tab keys -> integer threshold
//   2. ballot candidate lanes; loop set bits (~1 iter/row): broadcast col,
//      all 64 lanes fp32-dot z[row].emb[col] (z row lives in registers),
//      fold min-key
//   3. winner: re-read emb[best] (L2-hot), write quantized, (e-z)^2 loss
//      partials from registers, out_idx, one scattered histogram atomic/row
// ---------------------------------------------------------------------------
__global__ __launch_bounds__(256)
void rescore_gather_kernel(const float* __restrict__ z,
                           const float* __restrict__ emb,
                           const float* __restrict__ esf,
                           const unsigned long long* __restrict__ tab,
                           float* __restrict__ outq,
                           float* __restrict__ out_idx_f,
                           int* __restrict__ counts,
                           float* __restrict__ bsums)
{
    int t = threadIdx.x, lane = t & 63, w = t >> 6;
    int row = blockIdx.x * 4 + w;

    unsigned long long e = tab[(size_t)row * 64 + lane];
    unsigned k1 = (unsigned)(e >> 32), k2 = (unsigned)e;
    unsigned m = k1;
    #pragma unroll
    for (int mask = 1; mask <= 32; mask <<= 1) {
        unsigned o = (unsigned)__shfl_xor((int)m, mask, 64);
        m = umin_(m, o);
    }
    unsigned thr = m + ((unsigned)DELTA_INT << 7);
    unsigned long long m1 = __ballot(k1 <= thr);
    unsigned long long m2 = __ballot(k2 <= thr);

    const float4* zr = (const float4*)(z + (size_t)row * DIMS + lane * 8);
    float4 a0 = zr[0], a1 = zr[1];

    unsigned long long best = ~0ull;
    while (m1 | m2) {
        int src;
        unsigned kk;
        if (m1) {
            src = __ffsll((long long)m1) - 1;
            m1 &= m1 - 1;
            kk = (unsigned)__shfl((int)k1, src, 64);
        } else {
            src = __ffsll((long long)m2) - 1;
            m2 &= m2 - 1;
            kk = (unsigned)__shfl((int)k2, src, 64);
        }
        int col = src * 128 + (int)(kk & 127u);

        const float4* er = (const float4*)(emb + (size_t)col * DIMS + lane * 8);
        float4 b0 = er[0], b1v = er[1];
        float s = a0.x * b0.x;
        s = fmaf(a0.y, b0.y, s); s = fmaf(a0.z, b0.z, s);
        s = fmaf(a0.w, b0.w, s); s = fmaf(a1.x, b1v.x, s);
        s = fmaf(a1.y, b1v.y, s); s = fmaf(a1.z, b1v.z, s);
        s = fmaf(a1.w, b1v.w, s);
        #pragma unroll
        for (int mask = 32; mask; mask >>= 1) s += __shfl_xor(s, mask);
        float v = fmaf(-2.f, s, esf[col]);
        unsigned long long key =
            ((unsigned long long)fkey(v) << 32) | (unsigned)col;
        best = key < best ? key : best;
    }

    // ---- gather + loss for this row ----
    int idx = (int)(best & 0xFFFFFFFFull);
    if (lane == 0) {
        out_idx_f[row] = (float)idx;
        atomicAdd(&counts[idx], 1);
    }
    const float4* er = (const float4*)(emb + (size_t)idx * DIMS + lane * 8);
    float4 e0 = er[0], e1 = er[1];
    float4* qr = (float4*)(outq + (size_t)row * DIMS + lane * 8);
    qr[0] = e0;
    qr[1] = e1;
    float dx0 = e0.x - a0.x, dy0 = e0.y - a0.y;
    float dz0 = e0.z - a0.z, dw0 = e0.w - a0.w;
    float dx1 = e1.x - a1.x, dy1 = e1.y - a1.y;
    float dz1 = e1.z - a1.z, dw1 = e1.w - a1.w;
    float ls = dx0 * dx0 + dy0 * dy0 + dz0 * dz0 + dw0 * dw0 +
               dx1 * dx1 + dy1 * dy1 + dz1 * dz1 + dw1 * dw1;
    #pragma unroll
    for (int off = 32; off; off >>= 1) ls += __shfl_down(ls, off);
    __shared__ float wsum[4];
    if (lane == 0) wsum[w] = ls;
    __syncthreads();
    if (t == 0)
        bsums[blockIdx.x] = wsum[0] + wsum[1] + wsum[2] + wsum[3];
}

// ---------------------------------------------------------------------------
// K3: finalize scalars: vq_loss and perplexity (bsums now 4096 entries).
// ---------------------------------------------------------------------------
__global__ __launch_bounds__(256)
void finalize_kernel(const int* __restrict__ counts, const float* __restrict__ bsums,
                     float* __restrict__ out_scalars)
{
    int t = threadIdx.x;
    double ls = 0.0, ps = 0.0;
    for (int i = t; i < 8192; i += 256) {
        if (i < 4096) ls += (double)bsums[i];
        double avg = (double)counts[i] * (1.0 / 16384.0);
        ps += avg * log(avg + 1e-10);
    }
    #pragma unroll
    for (int off = 32; off; off >>= 1) {
        ls += __shfl_down(ls, off);
        ps += __shfl_down(ps, off);
    }
    __shared__ double l4[4], p4[4];
    if ((t & 63) == 0) { l4[t >> 6] = ls; p4[t >> 6] = ps; }
    __syncthreads();
    if (t == 0) {
        double L = l4[0] + l4[1] + l4[2] + l4[3];
        double P = p4[0] + p4[1] + p4[2] + p4[3];
        out_scalars[0] = (float)(1.25 * L / 8388608.0);
        out_scalars[1] = (float)exp(-P);
    }
}

// ---------------------------------------------------------------------------
// ws layout (bytes):
//   counts int[8192]  @ 131072  (32768)   (zeroed by prep)
//   bsums  f32[4096]  @ 164096  (16384)
//   esf    f32[8192]  @ 196864  (32768)
//   esq    i32[8192]  @ 229632  (32768)
// d_out scratch reuse (consumed before gather overwrites):
//   zi8 @ 0 (8MB) | ei8 @ 16777216 (4MB) | tab @ 25165824 (8MB)
// d_out final (floats): quantized[8388608] | vq_loss | perplexity | idx[16384]
// ---------------------------------------------------------------------------
extern "C" void kernel_launch(void* const* d_in, const int* in_sizes, int n_in,
                              void* d_out, int out_size, void* d_ws, size_t ws_size,
                              hipStream_t stream)
{
    const float* z   = (const float*)d_in[0];
    const float* emb = (const float*)d_in[1];

    float* out         = (float*)d_out;
    float* outq        = out;
    float* out_scalars = out + 8388608;
    float* out_idx     = out + 8388610;

    char* ob = (char*)d_out;
    signed char* zi8 = (signed char*)(ob + 0);
    signed char* ei8 = (signed char*)(ob + 16777216);
    unsigned long long* tab = (unsigned long long*)(ob + 25165824);

    char* ws = (char*)d_ws;
    int*   counts = (int*)  (ws + 131072);
    float* bsums  = (float*)(ws + 164096);
    float* esf    = (float*)(ws + 196864);
    int*   esq    = (int*)  (ws + 229632);

    prep_kernel<<<2816, 256, 0, stream>>>(z, emb, zi8, ei8, esf, esq, counts);
    screen_kernel<<<dim3(64, 64), 256, 0, stream>>>((const char*)zi8,
                                                    (const char*)ei8, esq, tab);
    rescore_gather_kernel<<<4096, 256, 0, stream>>>(z, emb, esf, tab, outq,
                                                    out_idx, counts, bsums);
    finalize_kernel<<<1, 256, 0, stream>>>(counts, bsums, out_scalars);
}